// Round 2
// 706.306 us; speedup vs baseline: 1.4276x; 1.4276x over previous
//
#include <hip/hip_runtime.h>
#include <stdint.h>

#define N_NODES 100000
#define N_EDGES 3200000
#define IN_DIM  81
#define HID     64
#define LAT     32
#define BN_EPS  1e-5f
#define NBUCKET 391      /* ceil(N_NODES/256) */
#define EPB     8192     /* edges per block in bucket passes */
#define NBLK_E  391      /* ceil(N_EDGES/EPB) */

__device__ __forceinline__ float bfu2f(unsigned short u) {
    return __uint_as_float(((uint32_t)u) << 16);
}
__device__ __forceinline__ unsigned short f2bfu(float f) {
    uint32_t x = __float_as_uint(f);
    return (unsigned short)((x + 0x7FFFu + ((x >> 16) & 1u)) >> 16);
}
__device__ __forceinline__ uint32_t pack2(float a, float b) {
    return (uint32_t)f2bfu(a) | ((uint32_t)f2bfu(b) << 16);
}
__device__ __forceinline__ float loadf(const void* p, size_t i, int fp32) {
    if (fp32) return ((const float*)p)[i];
    return bfu2f(((const unsigned short*)p)[i]);
}
__device__ __forceinline__ int load_dst(const void* ei, int f64, long e) {
    if (f64) return (int)(((const long long*)ei)[(size_t)N_EDGES + e]);
    return ((const int*)ei)[(size_t)N_EDGES + e];
}
__device__ __forceinline__ int load_src(const void* ei, int f64, long e) {
    if (f64) return (int)(((const long long*)ei)[e]);
    return ((const int*)ei)[e];
}

// unpack 8 bf16 (uint4) and fma into acc[8] with scalar weight d
__device__ __forceinline__ void fma8(float* acc, uint4 v, float d) {
    acc[0] = fmaf(__uint_as_float(v.x << 16), d, acc[0]);
    acc[1] = fmaf(__uint_as_float(v.x & 0xffff0000u), d, acc[1]);
    acc[2] = fmaf(__uint_as_float(v.y << 16), d, acc[2]);
    acc[3] = fmaf(__uint_as_float(v.y & 0xffff0000u), d, acc[3]);
    acc[4] = fmaf(__uint_as_float(v.z << 16), d, acc[4]);
    acc[5] = fmaf(__uint_as_float(v.z & 0xffff0000u), d, acc[5]);
    acc[6] = fmaf(__uint_as_float(v.w << 16), d, acc[6]);
    acc[7] = fmaf(__uint_as_float(v.w & 0xffff0000u), d, acc[7]);
}

__global__ void stamp_kernel(float* out, int n, float v) {
    int i = blockIdx.x * blockDim.x + threadIdx.x;
    if (i < n) out[i] = v;
}

// flags[0]: edge int64?  flags[1+b]: per-float-input fp32?
__global__ void detect_all(const int* ei_raw,
                           const void* x, const void* W1, const void* b1,
                           const void* g1, const void* be1, const void* W2,
                           const void* b2, const void* g2, const void* be2,
                           const void* Wmu, const void* bmu, const void* Wls,
                           const void* bls, int* flags) {
    if (blockIdx.x != 0) return;
    int t = threadIdx.x;
    if (t == 13) {
        int acc = 0;
        for (int k = 0; k < 128; k++) acc |= ei_raw[2 * k * 11003 + 1];
        flags[0] = (acc == 0) ? 1 : 0;
        return;
    }
    if (t >= 13) return;
    const void* bufs[13] = { x, W1, b1, g1, be1, W2, b2, g2, be2, Wmu, bmu, Wls, bls };
    const int   ns[13]   = { 512, 512, 64, 64, 64, 512, 64, 64, 64, 512, 32, 512, 32 };
    const unsigned short* u = (const unsigned short*)bufs[t];
    int n = ns[t];
    int evenZero = 0, oddNz = 0, anyNz = 0, big = 0;
    for (int i = 0; i < n; i++) {
        unsigned short s = u[i];
        if (s) anyNz = 1;
        if (i & 1) { if (s) oddNz = 1; }
        else {
            if ((s & 0x7F80u) == 0x7F80u) big = 1;
            else if (fabsf(bfu2f(s)) > 100.0f) big = 1;
            if (s == 0) evenZero++;
        }
    }
    int fp32 = 0;
    if (anyNz) {
        if (big) fp32 = 1;
        else if (evenZero >= n / 4 && oddNz) fp32 = 1;
    }
    flags[1 + t] = fp32;
}

// zero stats[256] and bcnt[391]; grid 2 x 256
__global__ void zero_misc(float* stats, int* bcnt) {
    int i = blockIdx.x * blockDim.x + threadIdx.x;
    if (i < 256) stats[i] = 0.0f;
    if (i < NBUCKET) bcnt[i] = 0;
}

__global__ void convert_weights(const void* W1, const void* W2,
                                const void* Wmu, const void* Wls,
                                const void* b1, const void* b2,
                                const void* bmu, const void* bls,
                                const int* flags,
                                float* W1f, float* W2f, float* Wcatf,
                                float* b1f, float* b2f, float* bcatf) {
    int i = blockIdx.x * blockDim.x + threadIdx.x;
    if (i < IN_DIM * HID) { W1f[i] = loadf(W1, i, flags[2]); return; }
    i -= IN_DIM * HID;
    if (i < HID * HID) { W2f[i] = loadf(W2, i, flags[6]); return; }
    i -= HID * HID;
    if (i < HID * HID) {
        int k = i >> 6;
        int j = i & 63;
        if (j < LAT) Wcatf[i] = loadf(Wmu, (size_t)k * LAT + j, flags[10]);
        else         Wcatf[i] = loadf(Wls, (size_t)k * LAT + (j - LAT), flags[12]);
        return;
    }
    i -= HID * HID;
    if (i < HID) { b1f[i] = loadf(b1, i, flags[3]); return; }
    i -= HID;
    if (i < HID) { b2f[i] = loadf(b2, i, flags[7]); return; }
    i -= HID;
    if (i < HID) {
        if (i < LAT) bcatf[i] = loadf(bmu, i, flags[11]);
        else         bcatf[i] = loadf(bls, i - LAT, flags[13]);
    }
}

// ---- bucketed CSR build (counting sort by dst>>8) ----
// K1: per-block LDS histogram of dst buckets -> global bucket counts
__global__ void bucket_hist(const void* ei, const int* flags, int* bcnt) {
    __shared__ int h[NBUCKET];
    for (int i = threadIdx.x; i < NBUCKET; i += 256) h[i] = 0;
    __syncthreads();
    int f64 = flags[0];
    long e0 = (long)blockIdx.x * EPB;
    for (int i = 0; i < EPB / 256; i++) {
        long e = e0 + i * 256 + threadIdx.x;
        if (e < N_EDGES) atomicAdd(&h[load_dst(ei, f64, e) >> 8], 1);
    }
    __syncthreads();
    for (int i = threadIdx.x; i < NBUCKET; i += 256)
        if (h[i]) atomicAdd(&bcnt[i], h[i]);
}

// K2: exclusive scan of 391 bucket counts (512-slot LDS scan, 256 threads)
__global__ void bucket_scan(const int* bcnt, int* bbase, int* bcur, int* row_start) {
    __shared__ int sd[512];
    int t = threadIdx.x;
    int v0 = (t < NBUCKET) ? bcnt[t] : 0;
    int v1 = (t + 256 < NBUCKET) ? bcnt[t + 256] : 0;
    sd[t] = v0;
    sd[t + 256] = v1;
    __syncthreads();
    for (int off = 1; off < 256; off <<= 1) {       // scan lower half
        int x = (t >= off) ? sd[t - off] : 0;
        __syncthreads();
        sd[t] += x;
        __syncthreads();
    }
    int low_total = sd[255];
    for (int off = 1; off < 256; off <<= 1) {       // scan upper half
        int x = (t >= off) ? sd[256 + t - off] : 0;
        __syncthreads();
        sd[256 + t] += x;
        __syncthreads();
    }
    if (t < NBUCKET) {
        int excl = sd[t] - v0;
        bbase[t] = excl;
        bcur[t] = excl;
    }
    int j = 256 + t;
    if (j < NBUCKET) {
        int excl = sd[j] + low_total - v1;
        bbase[j] = excl;
        bcur[j] = excl;
    }
    if (t == 0) {
        bbase[NBUCKET] = N_EDGES;
        row_start[N_NODES] = N_EDGES;
    }
}

// K3: scatter edges into bucket-contiguous staging; record = (dst&255)<<17 | src
__global__ void bucket_scatter(const void* ei, const int* flags, int* bcur,
                               int* staged) {
    __shared__ int h[NBUCKET];
    __shared__ int lbase[NBUCKET];
    __shared__ int cnt[NBUCKET];
    for (int i = threadIdx.x; i < NBUCKET; i += 256) { h[i] = 0; cnt[i] = 0; }
    __syncthreads();
    int f64 = flags[0];
    long e0 = (long)blockIdx.x * EPB;
    for (int i = 0; i < EPB / 256; i++) {
        long e = e0 + i * 256 + threadIdx.x;
        if (e < N_EDGES) atomicAdd(&h[load_dst(ei, f64, e) >> 8], 1);
    }
    __syncthreads();
    for (int i = threadIdx.x; i < NBUCKET; i += 256)
        lbase[i] = h[i] ? atomicAdd(&bcur[i], h[i]) : 0;
    __syncthreads();
    for (int i = 0; i < EPB / 256; i++) {
        long e = e0 + i * 256 + threadIdx.x;
        if (e < N_EDGES) {
            int d = load_dst(ei, f64, e);
            int s = load_src(ei, f64, e);
            int b = d >> 8;
            int off = atomicAdd(&cnt[b], 1);
            staged[lbase[b] + off] = ((d & 255) << 17) | s;
        }
    }
}

// K4: one block per bucket: LDS deg/scan/cursors -> dis, row_start, csr
__global__ void csr_build(const int* bbase, const int* staged, float* dis,
                          int* row_start, int* csr) {
    int b = blockIdx.x;
    int t = threadIdx.x;
    int n0 = b << 8;
    int nn = N_NODES - n0;
    if (nn > 256) nn = 256;
    int e0 = bbase[b];
    int e1 = bbase[b + 1];
    __shared__ int ldeg[256];
    __shared__ int lcur[256];
    __shared__ int sd[256];
    ldeg[t] = 0;
    __syncthreads();
    for (int i = e0 + t; i < e1; i += 256)
        atomicAdd(&ldeg[staged[i] >> 17], 1);
    __syncthreads();
    int v = ldeg[t];
    sd[t] = v;
    __syncthreads();
    for (int off = 1; off < 256; off <<= 1) {
        int x = (t >= off) ? sd[t - off] : 0;
        __syncthreads();
        sd[t] += x;
        __syncthreads();
    }
    int excl = sd[t] - v;
    if (t < nn) {
        dis[n0 + t] = rsqrtf((float)(v + 1));
        row_start[n0 + t] = e0 + excl;
    }
    lcur[t] = e0 + excl;
    __syncthreads();
    for (int i = e0 + t; i < e1; i += 256) {
        int rec = staged[i];
        int pos = atomicAdd(&lcur[rec >> 17], 1);
        csr[pos] = rec & 0x1FFFF;
    }
}

// ---- dense layers (T stored bf16, fp32 accumulate) ----
__global__ void gemm_l1(const void* X, const int* flags, const float* W,
                        unsigned short* T) {
    int r = blockIdx.x * blockDim.x + threadIdx.x;
    if (r >= N_NODES) return;
    int fp = flags[1];
    size_t base = (size_t)r * IN_DIM;
    float acc[HID];
    for (int j = 0; j < HID; j++) acc[j] = 0.0f;
    for (int k = 0; k < IN_DIM; k++) {
        float a = loadf(X, base + k, fp);
        const float* wr = W + k * HID;
        for (int j = 0; j < HID; j++) acc[j] += a * wr[j];
    }
    uint32_t* To = (uint32_t*)(T + (size_t)r * HID);
    for (int j = 0; j < HID / 2; j++) To[j] = pack2(acc[2 * j], acc[2 * j + 1]);
}

__global__ void gemm_bn(const float* F, const float* W,
                        const float* scale, const float* shift, unsigned short* T) {
    int r = blockIdx.x * blockDim.x + threadIdx.x;
    if (r >= N_NODES) return;
    const float* ar = F + (size_t)r * HID;
    float acc[HID];
    for (int j = 0; j < HID; j++) acc[j] = 0.0f;
    for (int k = 0; k < HID; k++) {
        float a = fmaxf(ar[k] * scale[k] + shift[k], 0.0f);
        const float* wr = W + k * HID;
        for (int j = 0; j < HID; j++) acc[j] += a * wr[j];
    }
    uint32_t* To = (uint32_t*)(T + (size_t)r * HID);
    for (int j = 0; j < HID / 2; j++) To[j] = pack2(acc[2 * j], acc[2 * j + 1]);
}

// ---- aggregation: one wave per node, lane = g*8+c ----
// g = lane>>3 : edge slot within a chunk of 8 edges
// c = lane&7  : feature chunk (8 bf16 = one uint4 = 16B)
// Each iteration processes 16 edges via two independent 8-edge chains
// (no ds_bpermute in the hot loop; uint4 gathers give 8x fewer mem instrs).
__global__ void agg_mid(const unsigned short* T, const int* row_start, const int* csr,
                        const float* dis, const float* bias, float* F) {
    int wid = (blockIdx.x * blockDim.x + threadIdx.x) >> 6;
    if (wid >= N_NODES) return;
    int lane = threadIdx.x & 63;
    int g = lane >> 3;
    int c = lane & 7;
    float dn = dis[wid];
    float acc[8];
#pragma unroll
    for (int k = 0; k < 8; k++) acc[k] = 0.0f;
    // self-loop term (weight dn inside acc; whole acc gets *dn at the end)
    if (g == 0) {
        uint4 v = ((const uint4*)(T + (size_t)wid * HID))[c];
        fma8(acc, v, dn);
    }
    int s0 = row_start[wid];
    int s1 = row_start[wid + 1];
    for (int e = s0; e < s1; e += 16) {
        int iA = e + g;
        int iB = e + 8 + g;
        int mA = iA < s1;
        int mB = iB < s1;
        int sA = csr[mA ? iA : s0];
        int sB = csr[mB ? iB : s0];
        float dA = mA ? dis[sA] : 0.0f;
        float dB = mB ? dis[sB] : 0.0f;
        uint4 vA = ((const uint4*)(T + (size_t)sA * HID))[c];
        uint4 vB = ((const uint4*)(T + (size_t)sB * HID))[c];
        fma8(acc, vA, dA);
        fma8(acc, vB, dB);
    }
    // reduce over the 8 edge-slot groups (xor strides 8,16,32)
#pragma unroll
    for (int k = 0; k < 8; k++) {
        float v = acc[k];
        v += __shfl_xor(v, 8);
        v += __shfl_xor(v, 16);
        v += __shfl_xor(v, 32);
        acc[k] = v;
    }
    if (g == 0) {
        const float4* bp = (const float4*)(bias + c * 8);
        float4 b0 = bp[0];
        float4 b1 = bp[1];
        float4 r0, r1;
        r0.x = b0.x + dn * acc[0];
        r0.y = b0.y + dn * acc[1];
        r0.z = b0.z + dn * acc[2];
        r0.w = b0.w + dn * acc[3];
        r1.x = b1.x + dn * acc[4];
        r1.y = b1.y + dn * acc[5];
        r1.z = b1.z + dn * acc[6];
        r1.w = b1.w + dn * acc[7];
        float4* o = (float4*)(F + (size_t)wid * HID + c * 8);
        o[0] = r0;
        o[1] = r1;
    }
}

__global__ void agg_out(const unsigned short* T, const int* row_start, const int* csr,
                        const float* dis, const float* bias, float* out) {
    int wid = (blockIdx.x * blockDim.x + threadIdx.x) >> 6;
    if (wid >= N_NODES) return;
    int lane = threadIdx.x & 63;
    int g = lane >> 3;
    int c = lane & 7;
    float dn = dis[wid];
    float acc[8];
#pragma unroll
    for (int k = 0; k < 8; k++) acc[k] = 0.0f;
    if (g == 0) {
        uint4 v = ((const uint4*)(T + (size_t)wid * HID))[c];
        fma8(acc, v, dn);
    }
    int s0 = row_start[wid];
    int s1 = row_start[wid + 1];
    for (int e = s0; e < s1; e += 16) {
        int iA = e + g;
        int iB = e + 8 + g;
        int mA = iA < s1;
        int mB = iB < s1;
        int sA = csr[mA ? iA : s0];
        int sB = csr[mB ? iB : s0];
        float dA = mA ? dis[sA] : 0.0f;
        float dB = mB ? dis[sB] : 0.0f;
        uint4 vA = ((const uint4*)(T + (size_t)sA * HID))[c];
        uint4 vB = ((const uint4*)(T + (size_t)sB * HID))[c];
        fma8(acc, vA, dA);
        fma8(acc, vB, dB);
    }
#pragma unroll
    for (int k = 0; k < 8; k++) {
        float v = acc[k];
        v += __shfl_xor(v, 8);
        v += __shfl_xor(v, 16);
        v += __shfl_xor(v, 32);
        acc[k] = v;
    }
    if (g == 0) {
        const float4* bp = (const float4*)(bias + c * 8);
        float4 b0 = bp[0];
        float4 b1 = bp[1];
        float4 r0, r1;
        r0.x = b0.x + dn * acc[0];
        r0.y = b0.y + dn * acc[1];
        r0.z = b0.z + dn * acc[2];
        r0.w = b0.w + dn * acc[3];
        r1.x = b1.x + dn * acc[4];
        r1.y = b1.y + dn * acc[5];
        r1.z = b1.z + dn * acc[6];
        r1.w = b1.w + dn * acc[7];
        float4* o;
        if (c < 4)
            o = (float4*)(out + (size_t)wid * LAT + c * 8);
        else
            o = (float4*)(out + (size_t)N_NODES * LAT + (size_t)wid * LAT + (c - 4) * 8);
        o[0] = r0;
        o[1] = r1;
    }
}

__global__ void stats_kernel(const float* F, float* stats) {
    int lane = threadIdx.x & 63;
    int wv = threadIdx.x >> 6;
    float s = 0.0f;
    float q = 0.0f;
    for (int r = blockIdx.x * 4 + wv; r < N_NODES; r += gridDim.x * 4) {
        float v = F[(size_t)r * HID + lane];
        s += v;
        q += v * v;
    }
    __shared__ float ls[256];
    __shared__ float lq[256];
    ls[threadIdx.x] = s;
    lq[threadIdx.x] = q;
    __syncthreads();
    if (threadIdx.x < 64) {
        s = ls[threadIdx.x] + ls[64 + threadIdx.x] + ls[128 + threadIdx.x] + ls[192 + threadIdx.x];
        q = lq[threadIdx.x] + lq[64 + threadIdx.x] + lq[128 + threadIdx.x] + lq[192 + threadIdx.x];
        atomicAdd(&stats[lane], s);
        atomicAdd(&stats[64 + lane], q);
    }
}

__global__ void finalize_bn(const float* stats, const void* g, const void* beta,
                            const int* flags, int gflag, int bflag,
                            float* scale, float* shift) {
    int j = threadIdx.x;
    if (j >= HID) return;
    float inv_n = 1.0f / (float)N_NODES;
    float mean = stats[j] * inv_n;
    float var = stats[64 + j] * inv_n - mean * mean;
    float sc = loadf(g, j, flags[gflag]) * rsqrtf(var + BN_EPS);
    scale[j] = sc;
    shift[j] = loadf(beta, j, flags[bflag]) - mean * sc;
}

extern "C" void kernel_launch(void* const* d_in, const int* in_sizes, int n_in,
                              void* d_out, int out_size, void* d_ws, size_t ws_size,
                              hipStream_t stream) {
    (void)in_sizes;
    (void)n_in;
    const void* x   = d_in[0];
    const void* ei  = d_in[1];
    const void* W1  = d_in[2];
    const void* b1  = d_in[3];
    const void* g1  = d_in[4];
    const void* be1 = d_in[5];
    const void* W2  = d_in[6];
    const void* b2  = d_in[7];
    const void* g2  = d_in[8];
    const void* be2 = d_in[9];
    const void* Wmu = d_in[10];
    const void* bmu = d_in[11];
    const void* Wls = d_in[12];
    const void* bls = d_in[13];
    float* out = (float*)d_out;

    char* base = (char*)d_ws;
    size_t off = 0;
    int* staged = (int*)(base + off);
    off += (size_t)N_EDGES * 4;        off = (off + 511) & ~(size_t)511;
    int* csr = (int*)(base + off);
    off += (size_t)N_EDGES * 4;        off = (off + 511) & ~(size_t)511;
    unsigned short* T = (unsigned short*)(base + off);
    off += (size_t)N_NODES * HID * 2;  off = (off + 511) & ~(size_t)511;
    float* F = (float*)(base + off);
    off += (size_t)N_NODES * HID * 4;  off = (off + 511) & ~(size_t)511;
    float* dis = (float*)(base + off);
    off += (size_t)N_NODES * 4;        off = (off + 511) & ~(size_t)511;
    int* row_start = (int*)(base + off);
    off += (size_t)(N_NODES + 1) * 4;  off = (off + 511) & ~(size_t)511;
    int* bcnt = (int*)(base + off);
    off += NBUCKET * 4;                off = (off + 511) & ~(size_t)511;
    int* bbase = (int*)(base + off);
    off += (NBUCKET + 1) * 4;          off = (off + 511) & ~(size_t)511;
    int* bcur = (int*)(base + off);
    off += NBUCKET * 4;                off = (off + 511) & ~(size_t)511;
    int* flags = (int*)(base + off);
    off += 512;                        off = (off + 511) & ~(size_t)511;
    float* W1f = (float*)(base + off);
    off += (size_t)IN_DIM * HID * 4;   off = (off + 511) & ~(size_t)511;
    float* W2f = (float*)(base + off);
    off += (size_t)HID * HID * 4;      off = (off + 511) & ~(size_t)511;
    float* Wcatf = (float*)(base + off);
    off += (size_t)HID * HID * 4;      off = (off + 511) & ~(size_t)511;
    float* b1f = (float*)(base + off);
    off += HID * 4;                    off = (off + 511) & ~(size_t)511;
    float* b2f = (float*)(base + off);
    off += HID * 4;                    off = (off + 511) & ~(size_t)511;
    float* bcatf = (float*)(base + off);
    off += HID * 4;                    off = (off + 511) & ~(size_t)511;
    float* stats = (float*)(base + off);
    off += 256 * 4;                    off = (off + 511) & ~(size_t)511;
    float* scale1 = (float*)(base + off);
    off += HID * 4;                    off = (off + 511) & ~(size_t)511;
    float* shift1 = (float*)(base + off);
    off += HID * 4;                    off = (off + 511) & ~(size_t)511;
    float* scale2 = (float*)(base + off);
    off += HID * 4;                    off = (off + 511) & ~(size_t)511;
    float* shift2 = (float*)(base + off);
    off += HID * 4;

    const int BT = 256;
    int gN   = (N_NODES + BT - 1) / BT;          // 391
    int gW   = (N_NODES * 64 + BT - 1) / BT;     // 25000
    int gOut = (out_size + BT - 1) / BT;
    int gCv  = (IN_DIM * HID + 2 * HID * HID + 3 * HID + BT - 1) / BT;

    if (ws_size < off) {
        stamp_kernel<<<gOut, BT, 0, stream>>>(out, out_size, 6.8e37f);
        return;
    }

    detect_all<<<1, 64, 0, stream>>>((const int*)ei, x, W1, b1, g1, be1, W2, b2,
                                     g2, be2, Wmu, bmu, Wls, bls, flags);
    zero_misc<<<2, BT, 0, stream>>>(stats, bcnt);
    convert_weights<<<gCv, BT, 0, stream>>>(W1, W2, Wmu, Wls, b1, b2, bmu, bls,
                                            flags, W1f, W2f, Wcatf, b1f, b2f, bcatf);

    // bucketed CSR build
    bucket_hist<<<NBLK_E, BT, 0, stream>>>(ei, flags, bcnt);
    bucket_scan<<<1, BT, 0, stream>>>(bcnt, bbase, bcur, row_start);
    bucket_scatter<<<NBLK_E, BT, 0, stream>>>(ei, flags, bcur, staged);
    csr_build<<<NBUCKET, BT, 0, stream>>>(bbase, staged, dis, row_start, csr);

    // layer 1
    gemm_l1<<<gN, BT, 0, stream>>>(x, flags, W1f, T);
    agg_mid<<<gW, BT, 0, stream>>>(T, row_start, csr, dis, b1f, F);
    stats_kernel<<<256, BT, 0, stream>>>(F, stats);
    finalize_bn<<<1, 64, 0, stream>>>(stats, g1, be1, flags, 4, 5, scale1, shift1);

    // layer 2
    gemm_bn<<<gN, BT, 0, stream>>>(F, W2f, scale1, shift1, T);
    agg_mid<<<gW, BT, 0, stream>>>(T, row_start, csr, dis, b2f, F);
    stats_kernel<<<256, BT, 0, stream>>>(F, stats + 128);
    finalize_bn<<<1, 64, 0, stream>>>(stats + 128, g2, be2, flags, 8, 9, scale2, shift2);

    // layer 3 -> output (fp32)
    gemm_bn<<<gN, BT, 0, stream>>>(F, Wcatf, scale2, shift2, T);
    agg_out<<<gW, BT, 0, stream>>>(T, row_start, csr, dis, bcatf, out);
}

// Round 3
// 702.055 us; speedup vs baseline: 1.4362x; 1.0061x over previous
//
#include <hip/hip_runtime.h>
#include <stdint.h>

#define N_NODES 100000
#define N_EDGES 3200000
#define IN_DIM  81
#define HID     64
#define LAT     32
#define BN_EPS  1e-5f
#define NBUCKET 391      /* ceil(N_NODES/256) */
#define EPB     8192     /* edges per block in bucket passes */
#define NBLK_E  391      /* ceil(N_EDGES/EPB) */

__device__ __forceinline__ float bfu2f(unsigned short u) {
    return __uint_as_float(((uint32_t)u) << 16);
}
__device__ __forceinline__ unsigned short f2bfu(float f) {
    uint32_t x = __float_as_uint(f);
    return (unsigned short)((x + 0x7FFFu + ((x >> 16) & 1u)) >> 16);
}
__device__ __forceinline__ float loadf(const void* p, size_t i, int fp32) {
    if (fp32) return ((const float*)p)[i];
    return bfu2f(((const unsigned short*)p)[i]);
}
__device__ __forceinline__ int load_dst(const void* ei, int f64, long e) {
    if (f64) return (int)(((const long long*)ei)[(size_t)N_EDGES + e]);
    return ((const int*)ei)[(size_t)N_EDGES + e];
}
__device__ __forceinline__ int load_src(const void* ei, int f64, long e) {
    if (f64) return (int)(((const long long*)ei)[e]);
    return ((const int*)ei)[e];
}
// wave-uniform broadcast of lane k's value (k must be compile-time constant)
__device__ __forceinline__ float bcast(float v, int k) {
    return __int_as_float(__builtin_amdgcn_readlane(__float_as_int(v), k));
}

// unpack 8 bf16 (uint4) and fma into acc[8] with scalar weight d
__device__ __forceinline__ void fma8(float* acc, uint4 v, float d) {
    acc[0] = fmaf(__uint_as_float(v.x << 16), d, acc[0]);
    acc[1] = fmaf(__uint_as_float(v.x & 0xffff0000u), d, acc[1]);
    acc[2] = fmaf(__uint_as_float(v.y << 16), d, acc[2]);
    acc[3] = fmaf(__uint_as_float(v.y & 0xffff0000u), d, acc[3]);
    acc[4] = fmaf(__uint_as_float(v.z << 16), d, acc[4]);
    acc[5] = fmaf(__uint_as_float(v.z & 0xffff0000u), d, acc[5]);
    acc[6] = fmaf(__uint_as_float(v.w << 16), d, acc[6]);
    acc[7] = fmaf(__uint_as_float(v.w & 0xffff0000u), d, acc[7]);
}

__global__ void stamp_kernel(float* out, int n, float v) {
    int i = blockIdx.x * blockDim.x + threadIdx.x;
    if (i < n) out[i] = v;
}

// flags[0]: edge int64?  flags[1+b]: per-float-input fp32?
__global__ void detect_all(const int* ei_raw,
                           const void* x, const void* W1, const void* b1,
                           const void* g1, const void* be1, const void* W2,
                           const void* b2, const void* g2, const void* be2,
                           const void* Wmu, const void* bmu, const void* Wls,
                           const void* bls, int* flags) {
    if (blockIdx.x != 0) return;
    int t = threadIdx.x;
    if (t == 13) {
        int acc = 0;
        for (int k = 0; k < 128; k++) acc |= ei_raw[2 * k * 11003 + 1];
        flags[0] = (acc == 0) ? 1 : 0;
        return;
    }
    if (t >= 13) return;
    const void* bufs[13] = { x, W1, b1, g1, be1, W2, b2, g2, be2, Wmu, bmu, Wls, bls };
    const int   ns[13]   = { 512, 512, 64, 64, 64, 512, 64, 64, 64, 512, 32, 512, 32 };
    const unsigned short* u = (const unsigned short*)bufs[t];
    int n = ns[t];
    int evenZero = 0, oddNz = 0, anyNz = 0, big = 0;
    for (int i = 0; i < n; i++) {
        unsigned short s = u[i];
        if (s) anyNz = 1;
        if (i & 1) { if (s) oddNz = 1; }
        else {
            if ((s & 0x7F80u) == 0x7F80u) big = 1;
            else if (fabsf(bfu2f(s)) > 100.0f) big = 1;
            if (s == 0) evenZero++;
        }
    }
    int fp32 = 0;
    if (anyNz) {
        if (big) fp32 = 1;
        else if (evenZero >= n / 4 && oddNz) fp32 = 1;
    }
    flags[1 + t] = fp32;
}

// zero stats[256] and bcnt[391]; grid 2 x 256
__global__ void zero_misc(float* stats, int* bcnt) {
    int i = blockIdx.x * blockDim.x + threadIdx.x;
    if (i < 256) stats[i] = 0.0f;
    if (i < NBUCKET) bcnt[i] = 0;
}

__global__ void convert_weights(const void* W1, const void* W2,
                                const void* Wmu, const void* Wls,
                                const void* b1, const void* b2,
                                const void* bmu, const void* bls,
                                const int* flags,
                                float* W1f, float* W2f, float* Wcatf,
                                float* b1f, float* b2f, float* bcatf) {
    int i = blockIdx.x * blockDim.x + threadIdx.x;
    if (i < IN_DIM * HID) { W1f[i] = loadf(W1, i, flags[2]); return; }
    i -= IN_DIM * HID;
    if (i < HID * HID) { W2f[i] = loadf(W2, i, flags[6]); return; }
    i -= HID * HID;
    if (i < HID * HID) {
        int k = i >> 6;
        int j = i & 63;
        if (j < LAT) Wcatf[i] = loadf(Wmu, (size_t)k * LAT + j, flags[10]);
        else         Wcatf[i] = loadf(Wls, (size_t)k * LAT + (j - LAT), flags[12]);
        return;
    }
    i -= HID * HID;
    if (i < HID) { b1f[i] = loadf(b1, i, flags[3]); return; }
    i -= HID;
    if (i < HID) { b2f[i] = loadf(b2, i, flags[7]); return; }
    i -= HID;
    if (i < HID) {
        if (i < LAT) bcatf[i] = loadf(bmu, i, flags[11]);
        else         bcatf[i] = loadf(bls, i - LAT, flags[13]);
    }
}

// ---- bucketed CSR build (counting sort by dst>>8) ----
// K1: per-block LDS histogram of dst buckets -> global bucket counts
__global__ void bucket_hist(const void* ei, const int* flags, int* bcnt) {
    __shared__ int h[NBUCKET];
    for (int i = threadIdx.x; i < NBUCKET; i += 256) h[i] = 0;
    __syncthreads();
    int f64 = flags[0];
    long e0 = (long)blockIdx.x * EPB;
    for (int i = 0; i < EPB / 256; i++) {
        long e = e0 + i * 256 + threadIdx.x;
        if (e < N_EDGES) atomicAdd(&h[load_dst(ei, f64, e) >> 8], 1);
    }
    __syncthreads();
    for (int i = threadIdx.x; i < NBUCKET; i += 256)
        if (h[i]) atomicAdd(&bcnt[i], h[i]);
}

// K2: exclusive scan of 391 bucket counts (512-slot LDS scan, 256 threads)
__global__ void bucket_scan(const int* bcnt, int* bbase, int* bcur, int* row_start) {
    __shared__ int sd[512];
    int t = threadIdx.x;
    int v0 = (t < NBUCKET) ? bcnt[t] : 0;
    int v1 = (t + 256 < NBUCKET) ? bcnt[t + 256] : 0;
    sd[t] = v0;
    sd[t + 256] = v1;
    __syncthreads();
    for (int off = 1; off < 256; off <<= 1) {       // scan lower half
        int x = (t >= off) ? sd[t - off] : 0;
        __syncthreads();
        sd[t] += x;
        __syncthreads();
    }
    int low_total = sd[255];
    for (int off = 1; off < 256; off <<= 1) {       // scan upper half
        int x = (t >= off) ? sd[256 + t - off] : 0;
        __syncthreads();
        sd[256 + t] += x;
        __syncthreads();
    }
    if (t < NBUCKET) {
        int excl = sd[t] - v0;
        bbase[t] = excl;
        bcur[t] = excl;
    }
    int j = 256 + t;
    if (j < NBUCKET) {
        int excl = sd[j] + low_total - v1;
        bbase[j] = excl;
        bcur[j] = excl;
    }
    if (t == 0) {
        bbase[NBUCKET] = N_EDGES;
        row_start[N_NODES] = N_EDGES;
    }
}

// K3: scatter edges into bucket-contiguous staging; record = (dst&255)<<17 | src
__global__ void bucket_scatter(const void* ei, const int* flags, int* bcur,
                               int* staged) {
    __shared__ int h[NBUCKET];
    __shared__ int lbase[NBUCKET];
    __shared__ int cnt[NBUCKET];
    for (int i = threadIdx.x; i < NBUCKET; i += 256) { h[i] = 0; cnt[i] = 0; }
    __syncthreads();
    int f64 = flags[0];
    long e0 = (long)blockIdx.x * EPB;
    for (int i = 0; i < EPB / 256; i++) {
        long e = e0 + i * 256 + threadIdx.x;
        if (e < N_EDGES) atomicAdd(&h[load_dst(ei, f64, e) >> 8], 1);
    }
    __syncthreads();
    for (int i = threadIdx.x; i < NBUCKET; i += 256)
        lbase[i] = h[i] ? atomicAdd(&bcur[i], h[i]) : 0;
    __syncthreads();
    for (int i = 0; i < EPB / 256; i++) {
        long e = e0 + i * 256 + threadIdx.x;
        if (e < N_EDGES) {
            int d = load_dst(ei, f64, e);
            int s = load_src(ei, f64, e);
            int b = d >> 8;
            int off = atomicAdd(&cnt[b], 1);
            staged[lbase[b] + off] = ((d & 255) << 17) | s;
        }
    }
}

// K4: one block per bucket: LDS deg/scan/cursors -> dis, row_start, csr
__global__ void csr_build(const int* bbase, const int* staged, float* dis,
                          int* row_start, int* csr) {
    int b = blockIdx.x;
    int t = threadIdx.x;
    int n0 = b << 8;
    int nn = N_NODES - n0;
    if (nn > 256) nn = 256;
    int e0 = bbase[b];
    int e1 = bbase[b + 1];
    __shared__ int ldeg[256];
    __shared__ int lcur[256];
    __shared__ int sd[256];
    ldeg[t] = 0;
    __syncthreads();
    for (int i = e0 + t; i < e1; i += 256)
        atomicAdd(&ldeg[staged[i] >> 17], 1);
    __syncthreads();
    int v = ldeg[t];
    sd[t] = v;
    __syncthreads();
    for (int off = 1; off < 256; off <<= 1) {
        int x = (t >= off) ? sd[t - off] : 0;
        __syncthreads();
        sd[t] += x;
        __syncthreads();
    }
    int excl = sd[t] - v;
    if (t < nn) {
        dis[n0 + t] = rsqrtf((float)(v + 1));
        row_start[n0 + t] = e0 + excl;
    }
    lcur[t] = e0 + excl;
    __syncthreads();
    for (int i = e0 + t; i < e1; i += 256) {
        int rec = staged[i];
        int pos = atomicAdd(&lcur[rec >> 17], 1);
        csr[pos] = rec & 0x1FFFF;
    }
}

// ---- dense layers: one wave per node, lane = output feature ----
// Inner loop: v_readlane broadcast of activation k + coalesced 4B W load + fma.
// Single-register accumulator -> full occupancy (100k waves).
__global__ void gemm_l1(const void* X, const int* flags, const float* W,
                        unsigned short* T) {
    int wid = (blockIdx.x * blockDim.x + threadIdx.x) >> 6;
    if (wid >= N_NODES) return;
    int lane = threadIdx.x & 63;
    int fp = flags[1];
    size_t base = (size_t)wid * IN_DIM;
    // lane-parallel load of the x row (81 values across 64 lanes)
    float xa = loadf(X, base + lane, fp);
    float xb = (lane < IN_DIM - 64) ? loadf(X, base + 64 + lane, fp) : 0.0f;
    float acc = 0.0f;
    const float* Wp = W + lane;
#pragma unroll
    for (int k = 0; k < 64; k++) {
        float a = bcast(xa, k);
        acc = fmaf(a, Wp[k * HID], acc);
    }
#pragma unroll
    for (int k = 0; k < IN_DIM - 64; k++) {
        float a = bcast(xb, k);
        acc = fmaf(a, Wp[(64 + k) * HID], acc);
    }
    T[(size_t)wid * HID + lane] = f2bfu(acc);
}

__global__ void gemm_bn(const float* F, const float* W,
                        const float* scale, const float* shift, unsigned short* T) {
    int wid = (blockIdx.x * blockDim.x + threadIdx.x) >> 6;
    if (wid >= N_NODES) return;
    int lane = threadIdx.x & 63;
    // lane loads + normalizes its own activation element once
    float f = F[(size_t)wid * HID + lane];
    float a_own = fmaxf(f * scale[lane] + shift[lane], 0.0f);
    float acc = 0.0f;
    const float* Wp = W + lane;
#pragma unroll
    for (int k = 0; k < HID; k++) {
        float a = bcast(a_own, k);
        acc = fmaf(a, Wp[k * HID], acc);
    }
    T[(size_t)wid * HID + lane] = f2bfu(acc);
}

// ---- aggregation: one wave per node, lane = g*8+c ----
// g = lane>>3 : edge slot within a chunk of 8 edges
// c = lane&7  : feature chunk (8 bf16 = one uint4 = 16B)
__global__ void agg_mid(const unsigned short* T, const int* row_start, const int* csr,
                        const float* dis, const float* bias, float* F) {
    int wid = (blockIdx.x * blockDim.x + threadIdx.x) >> 6;
    if (wid >= N_NODES) return;
    int lane = threadIdx.x & 63;
    int g = lane >> 3;
    int c = lane & 7;
    float dn = dis[wid];
    float acc[8];
#pragma unroll
    for (int k = 0; k < 8; k++) acc[k] = 0.0f;
    // self-loop term (weight dn inside acc; whole acc gets *dn at the end)
    if (g == 0) {
        uint4 v = ((const uint4*)(T + (size_t)wid * HID))[c];
        fma8(acc, v, dn);
    }
    int s0 = row_start[wid];
    int s1 = row_start[wid + 1];
    for (int e = s0; e < s1; e += 16) {
        int iA = e + g;
        int iB = e + 8 + g;
        int mA = iA < s1;
        int mB = iB < s1;
        int sA = csr[mA ? iA : s0];
        int sB = csr[mB ? iB : s0];
        float dA = mA ? dis[sA] : 0.0f;
        float dB = mB ? dis[sB] : 0.0f;
        uint4 vA = ((const uint4*)(T + (size_t)sA * HID))[c];
        uint4 vB = ((const uint4*)(T + (size_t)sB * HID))[c];
        fma8(acc, vA, dA);
        fma8(acc, vB, dB);
    }
    // reduce over the 8 edge-slot groups (xor strides 8,16,32)
#pragma unroll
    for (int k = 0; k < 8; k++) {
        float v = acc[k];
        v += __shfl_xor(v, 8);
        v += __shfl_xor(v, 16);
        v += __shfl_xor(v, 32);
        acc[k] = v;
    }
    if (g == 0) {
        const float4* bp = (const float4*)(bias + c * 8);
        float4 b0 = bp[0];
        float4 b1 = bp[1];
        float4 r0, r1;
        r0.x = b0.x + dn * acc[0];
        r0.y = b0.y + dn * acc[1];
        r0.z = b0.z + dn * acc[2];
        r0.w = b0.w + dn * acc[3];
        r1.x = b1.x + dn * acc[4];
        r1.y = b1.y + dn * acc[5];
        r1.z = b1.z + dn * acc[6];
        r1.w = b1.w + dn * acc[7];
        float4* o = (float4*)(F + (size_t)wid * HID + c * 8);
        o[0] = r0;
        o[1] = r1;
    }
}

__global__ void agg_out(const unsigned short* T, const int* row_start, const int* csr,
                        const float* dis, const float* bias, float* out) {
    int wid = (blockIdx.x * blockDim.x + threadIdx.x) >> 6;
    if (wid >= N_NODES) return;
    int lane = threadIdx.x & 63;
    int g = lane >> 3;
    int c = lane & 7;
    float dn = dis[wid];
    float acc[8];
#pragma unroll
    for (int k = 0; k < 8; k++) acc[k] = 0.0f;
    if (g == 0) {
        uint4 v = ((const uint4*)(T + (size_t)wid * HID))[c];
        fma8(acc, v, dn);
    }
    int s0 = row_start[wid];
    int s1 = row_start[wid + 1];
    for (int e = s0; e < s1; e += 16) {
        int iA = e + g;
        int iB = e + 8 + g;
        int mA = iA < s1;
        int mB = iB < s1;
        int sA = csr[mA ? iA : s0];
        int sB = csr[mB ? iB : s0];
        float dA = mA ? dis[sA] : 0.0f;
        float dB = mB ? dis[sB] : 0.0f;
        uint4 vA = ((const uint4*)(T + (size_t)sA * HID))[c];
        uint4 vB = ((const uint4*)(T + (size_t)sB * HID))[c];
        fma8(acc, vA, dA);
        fma8(acc, vB, dB);
    }
#pragma unroll
    for (int k = 0; k < 8; k++) {
        float v = acc[k];
        v += __shfl_xor(v, 8);
        v += __shfl_xor(v, 16);
        v += __shfl_xor(v, 32);
        acc[k] = v;
    }
    if (g == 0) {
        const float4* bp = (const float4*)(bias + c * 8);
        float4 b0 = bp[0];
        float4 b1 = bp[1];
        float4 r0, r1;
        r0.x = b0.x + dn * acc[0];
        r0.y = b0.y + dn * acc[1];
        r0.z = b0.z + dn * acc[2];
        r0.w = b0.w + dn * acc[3];
        r1.x = b1.x + dn * acc[4];
        r1.y = b1.y + dn * acc[5];
        r1.z = b1.z + dn * acc[6];
        r1.w = b1.w + dn * acc[7];
        float4* o;
        if (c < 4)
            o = (float4*)(out + (size_t)wid * LAT + c * 8);
        else
            o = (float4*)(out + (size_t)N_NODES * LAT + (size_t)wid * LAT + (c - 4) * 8);
        o[0] = r0;
        o[1] = r1;
    }
}

__global__ void stats_kernel(const float* F, float* stats) {
    int lane = threadIdx.x & 63;
    int wv = threadIdx.x >> 6;
    float s = 0.0f;
    float q = 0.0f;
    for (int r = blockIdx.x * 4 + wv; r < N_NODES; r += gridDim.x * 4) {
        float v = F[(size_t)r * HID + lane];
        s += v;
        q += v * v;
    }
    __shared__ float ls[256];
    __shared__ float lq[256];
    ls[threadIdx.x] = s;
    lq[threadIdx.x] = q;
    __syncthreads();
    if (threadIdx.x < 64) {
        s = ls[threadIdx.x] + ls[64 + threadIdx.x] + ls[128 + threadIdx.x] + ls[192 + threadIdx.x];
        q = lq[threadIdx.x] + lq[64 + threadIdx.x] + lq[128 + threadIdx.x] + lq[192 + threadIdx.x];
        atomicAdd(&stats[lane], s);
        atomicAdd(&stats[64 + lane], q);
    }
}

__global__ void finalize_bn(const float* stats, const void* g, const void* beta,
                            const int* flags, int gflag, int bflag,
                            float* scale, float* shift) {
    int j = threadIdx.x;
    if (j >= HID) return;
    float inv_n = 1.0f / (float)N_NODES;
    float mean = stats[j] * inv_n;
    float var = stats[64 + j] * inv_n - mean * mean;
    float sc = loadf(g, j, flags[gflag]) * rsqrtf(var + BN_EPS);
    scale[j] = sc;
    shift[j] = loadf(beta, j, flags[bflag]) - mean * sc;
}

extern "C" void kernel_launch(void* const* d_in, const int* in_sizes, int n_in,
                              void* d_out, int out_size, void* d_ws, size_t ws_size,
                              hipStream_t stream) {
    (void)in_sizes;
    (void)n_in;
    const void* x   = d_in[0];
    const void* ei  = d_in[1];
    const void* W1  = d_in[2];
    const void* b1  = d_in[3];
    const void* g1  = d_in[4];
    const void* be1 = d_in[5];
    const void* W2  = d_in[6];
    const void* b2  = d_in[7];
    const void* g2  = d_in[8];
    const void* be2 = d_in[9];
    const void* Wmu = d_in[10];
    const void* bmu = d_in[11];
    const void* Wls = d_in[12];
    const void* bls = d_in[13];
    float* out = (float*)d_out;

    char* base = (char*)d_ws;
    size_t off = 0;
    int* staged = (int*)(base + off);
    off += (size_t)N_EDGES * 4;        off = (off + 511) & ~(size_t)511;
    int* csr = (int*)(base + off);
    off += (size_t)N_EDGES * 4;        off = (off + 511) & ~(size_t)511;
    unsigned short* T = (unsigned short*)(base + off);
    off += (size_t)N_NODES * HID * 2;  off = (off + 511) & ~(size_t)511;
    float* F = (float*)(base + off);
    off += (size_t)N_NODES * HID * 4;  off = (off + 511) & ~(size_t)511;
    float* dis = (float*)(base + off);
    off += (size_t)N_NODES * 4;        off = (off + 511) & ~(size_t)511;
    int* row_start = (int*)(base + off);
    off += (size_t)(N_NODES + 1) * 4;  off = (off + 511) & ~(size_t)511;
    int* bcnt = (int*)(base + off);
    off += NBUCKET * 4;                off = (off + 511) & ~(size_t)511;
    int* bbase = (int*)(base + off);
    off += (NBUCKET + 1) * 4;          off = (off + 511) & ~(size_t)511;
    int* bcur = (int*)(base + off);
    off += NBUCKET * 4;                off = (off + 511) & ~(size_t)511;
    int* flags = (int*)(base + off);
    off += 512;                        off = (off + 511) & ~(size_t)511;
    float* W1f = (float*)(base + off);
    off += (size_t)IN_DIM * HID * 4;   off = (off + 511) & ~(size_t)511;
    float* W2f = (float*)(base + off);
    off += (size_t)HID * HID * 4;      off = (off + 511) & ~(size_t)511;
    float* Wcatf = (float*)(base + off);
    off += (size_t)HID * HID * 4;      off = (off + 511) & ~(size_t)511;
    float* b1f = (float*)(base + off);
    off += HID * 4;                    off = (off + 511) & ~(size_t)511;
    float* b2f = (float*)(base + off);
    off += HID * 4;                    off = (off + 511) & ~(size_t)511;
    float* bcatf = (float*)(base + off);
    off += HID * 4;                    off = (off + 511) & ~(size_t)511;
    float* stats = (float*)(base + off);
    off += 256 * 4;                    off = (off + 511) & ~(size_t)511;
    float* scale1 = (float*)(base + off);
    off += HID * 4;                    off = (off + 511) & ~(size_t)511;
    float* shift1 = (float*)(base + off);
    off += HID * 4;                    off = (off + 511) & ~(size_t)511;
    float* scale2 = (float*)(base + off);
    off += HID * 4;                    off = (off + 511) & ~(size_t)511;
    float* shift2 = (float*)(base + off);
    off += HID * 4;

    const int BT = 256;
    int gW   = (N_NODES * 64 + BT - 1) / BT;     // 25000 (wave per node)
    int gOut = (out_size + BT - 1) / BT;
    int gCv  = (IN_DIM * HID + 2 * HID * HID + 3 * HID + BT - 1) / BT;

    if (ws_size < off) {
        stamp_kernel<<<gOut, BT, 0, stream>>>(out, out_size, 6.8e37f);
        return;
    }

    detect_all<<<1, 64, 0, stream>>>((const int*)ei, x, W1, b1, g1, be1, W2, b2,
                                     g2, be2, Wmu, bmu, Wls, bls, flags);
    zero_misc<<<2, BT, 0, stream>>>(stats, bcnt);
    convert_weights<<<gCv, BT, 0, stream>>>(W1, W2, Wmu, Wls, b1, b2, bmu, bls,
                                            flags, W1f, W2f, Wcatf, b1f, b2f, bcatf);

    // bucketed CSR build
    bucket_hist<<<NBLK_E, BT, 0, stream>>>(ei, flags, bcnt);
    bucket_scan<<<1, BT, 0, stream>>>(bcnt, bbase, bcur, row_start);
    bucket_scatter<<<NBLK_E, BT, 0, stream>>>(ei, flags, bcur, staged);
    csr_build<<<NBUCKET, BT, 0, stream>>>(bbase, staged, dis, row_start, csr);

    // layer 1
    gemm_l1<<<gW, BT, 0, stream>>>(x, flags, W1f, T);
    agg_mid<<<gW, BT, 0, stream>>>(T, row_start, csr, dis, b1f, F);
    stats_kernel<<<256, BT, 0, stream>>>(F, stats);
    finalize_bn<<<1, 64, 0, stream>>>(stats, g1, be1, flags, 4, 5, scale1, shift1);

    // layer 2
    gemm_bn<<<gW, BT, 0, stream>>>(F, W2f, scale1, shift1, T);
    agg_mid<<<gW, BT, 0, stream>>>(T, row_start, csr, dis, b2f, F);
    stats_kernel<<<256, BT, 0, stream>>>(F, stats + 128);
    finalize_bn<<<1, 64, 0, stream>>>(stats + 128, g2, be2, flags, 8, 9, scale2, shift2);

    // layer 3 -> output (fp32)
    gemm_bn<<<gW, BT, 0, stream>>>(F, Wcatf, scale2, shift2, T);
    agg_out<<<gW, BT, 0, stream>>>(T, row_start, csr, dis, bcatf, out);
}

// Round 5
// 553.713 us; speedup vs baseline: 1.8210x; 1.2679x over previous
//
#include <hip/hip_runtime.h>
#include <stdint.h>

#define N_NODES 100000
#define N_EDGES 3200000
#define IN_DIM  81
#define HID     64
#define LAT     32
#define BN_EPS  1e-5f
#define NBUCKET 391      /* ceil(N_NODES/256) */
#define EPB     8192     /* edges per block in bucket passes */
#define NBLK_E  391      /* ceil(N_EDGES/EPB) */

__device__ __forceinline__ float bfu2f(unsigned short u) {
    return __uint_as_float(((uint32_t)u) << 16);
}
__device__ __forceinline__ unsigned short f2bfu(float f) {
    uint32_t x = __float_as_uint(f);
    return (unsigned short)((x + 0x7FFFu + ((x >> 16) & 1u)) >> 16);
}
__device__ __forceinline__ float loadf(const void* p, size_t i, int fp32) {
    if (fp32) return ((const float*)p)[i];
    return bfu2f(((const unsigned short*)p)[i]);
}
__device__ __forceinline__ int load_dst(const void* ei, int f64, long e) {
    if (f64) return (int)(((const long long*)ei)[(size_t)N_EDGES + e]);
    return ((const int*)ei)[(size_t)N_EDGES + e];
}
__device__ __forceinline__ int load_src(const void* ei, int f64, long e) {
    if (f64) return (int)(((const long long*)ei)[e]);
    return ((const int*)ei)[e];
}
// wave-uniform broadcast of lane k's value (k must be compile-time constant)
__device__ __forceinline__ float bcast(float v, int k) {
    return __int_as_float(__builtin_amdgcn_readlane(__float_as_int(v), k));
}

// unpack 8 bf16 (uint4) and fma into acc[8] with scalar weight d
__device__ __forceinline__ void fma8(float* acc, uint4 v, float d) {
    acc[0] = fmaf(__uint_as_float(v.x << 16), d, acc[0]);
    acc[1] = fmaf(__uint_as_float(v.x & 0xffff0000u), d, acc[1]);
    acc[2] = fmaf(__uint_as_float(v.y << 16), d, acc[2]);
    acc[3] = fmaf(__uint_as_float(v.y & 0xffff0000u), d, acc[3]);
    acc[4] = fmaf(__uint_as_float(v.z << 16), d, acc[4]);
    acc[5] = fmaf(__uint_as_float(v.z & 0xffff0000u), d, acc[5]);
    acc[6] = fmaf(__uint_as_float(v.w << 16), d, acc[6]);
    acc[7] = fmaf(__uint_as_float(v.w & 0xffff0000u), d, acc[7]);
}

__global__ void stamp_kernel(float* out, int n, float v) {
    int i = blockIdx.x * blockDim.x + threadIdx.x;
    if (i < n) out[i] = v;
}

// flags[0]: edge int64?  flags[1+b]: per-float-input fp32?
// One wave per buffer (w=0..12) + one wave (w=13) for the edge-dtype probe.
// Lane-parallel loads, ballot/shfl reductions -> latency-bound no more.
__global__ void detect_all(const int* ei_raw,
                           const void* x, const void* W1, const void* b1,
                           const void* g1, const void* be1, const void* W2,
                           const void* b2, const void* g2, const void* be2,
                           const void* Wmu, const void* bmu, const void* Wls,
                           const void* bls, int* flags) {
    int w = threadIdx.x >> 6;
    int lane = threadIdx.x & 63;
    if (w == 13) {
        int acc = ei_raw[2 * lane * 11003 + 1] |
                  ei_raw[2 * (lane + 64) * 11003 + 1];
        unsigned long long b = __ballot(acc != 0);
        if (lane == 0) flags[0] = (b == 0ull) ? 1 : 0;
        return;
    }
    if (w > 13) return;
    const void* bufs[13] = { x, W1, b1, g1, be1, W2, b2, g2, be2, Wmu, bmu, Wls, bls };
    const int   ns[13]   = { 512, 512, 64, 64, 64, 512, 64, 64, 64, 512, 32, 512, 32 };
    const unsigned short* u = (const unsigned short*)bufs[w];
    int n = ns[w];
    int evenZero = 0;
    bool oddNz = false, anyNz = false, big = false;
    for (int i = lane; i < n; i += 64) {
        unsigned short s = u[i];
        if (s) anyNz = true;
        if (i & 1) { if (s) oddNz = true; }
        else {
            if ((s & 0x7F80u) == 0x7F80u) big = true;
            else if (fabsf(bfu2f(s)) > 100.0f) big = true;
            if (s == 0) evenZero++;
        }
    }
    unsigned long long anyB = __ballot(anyNz);
    unsigned long long oddB = __ballot(oddNz);
    unsigned long long bigB = __ballot(big);
#pragma unroll
    for (int o = 1; o < 64; o <<= 1) evenZero += __shfl_xor(evenZero, o);
    if (lane == 0) {
        int fp32 = 0;
        if (anyB != 0ull) {
            if (bigB != 0ull) fp32 = 1;
            else if (evenZero >= n / 4 && oddB != 0ull) fp32 = 1;
        }
        flags[1 + w] = fp32;
    }
}

// zero stats[256] and bcnt[391]; grid 2 x 256
__global__ void zero_misc(float* stats, int* bcnt) {
    int i = blockIdx.x * blockDim.x + threadIdx.x;
    if (i < 256) stats[i] = 0.0f;
    if (i < NBUCKET) bcnt[i] = 0;
}

__global__ void convert_weights(const void* W1, const void* W2,
                                const void* Wmu, const void* Wls,
                                const void* b1, const void* b2,
                                const void* bmu, const void* bls,
                                const int* flags,
                                float* W1f, float* W2f, float* Wcatf,
                                float* b1f, float* b2f, float* bcatf) {
    int i = blockIdx.x * blockDim.x + threadIdx.x;
    if (i < IN_DIM * HID) { W1f[i] = loadf(W1, i, flags[2]); return; }
    i -= IN_DIM * HID;
    if (i < HID * HID) { W2f[i] = loadf(W2, i, flags[6]); return; }
    i -= HID * HID;
    if (i < HID * HID) {
        int k = i >> 6;
        int j = i & 63;
        if (j < LAT) Wcatf[i] = loadf(Wmu, (size_t)k * LAT + j, flags[10]);
        else         Wcatf[i] = loadf(Wls, (size_t)k * LAT + (j - LAT), flags[12]);
        return;
    }
    i -= HID * HID;
    if (i < HID) { b1f[i] = loadf(b1, i, flags[3]); return; }
    i -= HID;
    if (i < HID) { b2f[i] = loadf(b2, i, flags[7]); return; }
    i -= HID;
    if (i < HID) {
        if (i < LAT) bcatf[i] = loadf(bmu, i, flags[11]);
        else         bcatf[i] = loadf(bls, i - LAT, flags[13]);
    }
}

// ---- bucketed CSR build (counting sort by dst>>8) ----
// K1: per-block LDS histogram of dst buckets -> global bucket counts
__global__ void bucket_hist(const void* ei, const int* flags, int* bcnt) {
    __shared__ int h[NBUCKET];
    for (int i = threadIdx.x; i < NBUCKET; i += 256) h[i] = 0;
    __syncthreads();
    int f64 = flags[0];
    long e0 = (long)blockIdx.x * EPB;
    for (int i = 0; i < EPB / 256; i++) {
        long e = e0 + i * 256 + threadIdx.x;
        if (e < N_EDGES) atomicAdd(&h[load_dst(ei, f64, e) >> 8], 1);
    }
    __syncthreads();
    for (int i = threadIdx.x; i < NBUCKET; i += 256)
        if (h[i]) atomicAdd(&bcnt[i], h[i]);
}

// K2: exclusive scan of 391 bucket counts (512-slot LDS scan, 256 threads)
__global__ void bucket_scan(const int* bcnt, int* bbase, int* bcur, int* row_start) {
    __shared__ int sd[512];
    int t = threadIdx.x;
    int v0 = (t < NBUCKET) ? bcnt[t] : 0;
    int v1 = (t + 256 < NBUCKET) ? bcnt[t + 256] : 0;
    sd[t] = v0;
    sd[t + 256] = v1;
    __syncthreads();
    for (int off = 1; off < 256; off <<= 1) {       // scan lower half
        int x = (t >= off) ? sd[t - off] : 0;
        __syncthreads();
        sd[t] += x;
        __syncthreads();
    }
    int low_total = sd[255];
    for (int off = 1; off < 256; off <<= 1) {       // scan upper half
        int x = (t >= off) ? sd[256 + t - off] : 0;
        __syncthreads();
        sd[256 + t] += x;
        __syncthreads();
    }
    if (t < NBUCKET) {
        int excl = sd[t] - v0;
        bbase[t] = excl;
        bcur[t] = excl;
    }
    int j = 256 + t;
    if (j < NBUCKET) {
        int excl = sd[j] + low_total - v1;
        bbase[j] = excl;
        bcur[j] = excl;
    }
    if (t == 0) {
        bbase[NBUCKET] = N_EDGES;
        row_start[N_NODES] = N_EDGES;
    }
}

// K3: scatter edges into bucket-contiguous staging; record = (dst&255)<<17 | src
__global__ void bucket_scatter(const void* ei, const int* flags, int* bcur,
                               int* staged) {
    __shared__ int h[NBUCKET];
    __shared__ int lbase[NBUCKET];
    __shared__ int cnt[NBUCKET];
    for (int i = threadIdx.x; i < NBUCKET; i += 256) { h[i] = 0; cnt[i] = 0; }
    __syncthreads();
    int f64 = flags[0];
    long e0 = (long)blockIdx.x * EPB;
    for (int i = 0; i < EPB / 256; i++) {
        long e = e0 + i * 256 + threadIdx.x;
        if (e < N_EDGES) atomicAdd(&h[load_dst(ei, f64, e) >> 8], 1);
    }
    __syncthreads();
    for (int i = threadIdx.x; i < NBUCKET; i += 256)
        lbase[i] = h[i] ? atomicAdd(&bcur[i], h[i]) : 0;
    __syncthreads();
    for (int i = 0; i < EPB / 256; i++) {
        long e = e0 + i * 256 + threadIdx.x;
        if (e < N_EDGES) {
            int d = load_dst(ei, f64, e);
            int s = load_src(ei, f64, e);
            int b = d >> 8;
            int off = atomicAdd(&cnt[b], 1);
            staged[lbase[b] + off] = ((d & 255) << 17) | s;
        }
    }
}

// K4: one block per bucket: LDS deg/scan/cursors -> dis, row_start, csr
__global__ void csr_build(const int* bbase, const int* staged, float* dis,
                          int* row_start, int* csr) {
    int b = blockIdx.x;
    int t = threadIdx.x;
    int n0 = b << 8;
    int nn = N_NODES - n0;
    if (nn > 256) nn = 256;
    int e0 = bbase[b];
    int e1 = bbase[b + 1];
    __shared__ int ldeg[256];
    __shared__ int lcur[256];
    __shared__ int sd[256];
    ldeg[t] = 0;
    __syncthreads();
    for (int i = e0 + t; i < e1; i += 256)
        atomicAdd(&ldeg[staged[i] >> 17], 1);
    __syncthreads();
    int v = ldeg[t];
    sd[t] = v;
    __syncthreads();
    for (int off = 1; off < 256; off <<= 1) {
        int x = (t >= off) ? sd[t - off] : 0;
        __syncthreads();
        sd[t] += x;
        __syncthreads();
    }
    int excl = sd[t] - v;
    if (t < nn) {
        dis[n0 + t] = rsqrtf((float)(v + 1));
        row_start[n0 + t] = e0 + excl;
    }
    lcur[t] = e0 + excl;
    __syncthreads();
    for (int i = e0 + t; i < e1; i += 256) {
        int rec = staged[i];
        int pos = atomicAdd(&lcur[rec >> 17], 1);
        csr[pos] = rec & 0x1FFFF;
    }
}

// ---- dense layers: one wave per 4 nodes, lane = output feature ----
// Each W-row load (256B/wave, L1-resident) is reused by 4 nodes ->
// 4x less L1 traffic than wave-per-node; readlane broadcast per node.
__global__ void gemm_l1(const void* X, const int* flags, const float* W,
                        unsigned short* T) {
    int wid = (blockIdx.x * blockDim.x + threadIdx.x) >> 6;
    int n0 = wid * 4;
    if (n0 >= N_NODES) return;
    int lane = threadIdx.x & 63;
    int fp = flags[1];
    float xa[4], xb[4];
#pragma unroll
    for (int nn = 0; nn < 4; nn++) {
        size_t base = (size_t)(n0 + nn) * IN_DIM;
        xa[nn] = loadf(X, base + lane, fp);
        xb[nn] = (lane < IN_DIM - 64) ? loadf(X, base + 64 + lane, fp) : 0.0f;
    }
    float acc[4] = { 0.0f, 0.0f, 0.0f, 0.0f };
    const float* Wp = W + lane;
#pragma unroll
    for (int k = 0; k < 64; k++) {
        float w = Wp[k * HID];
#pragma unroll
        for (int nn = 0; nn < 4; nn++)
            acc[nn] = fmaf(bcast(xa[nn], k), w, acc[nn]);
    }
#pragma unroll
    for (int k = 0; k < IN_DIM - 64; k++) {
        float w = Wp[(64 + k) * HID];
#pragma unroll
        for (int nn = 0; nn < 4; nn++)
            acc[nn] = fmaf(bcast(xb[nn], k), w, acc[nn]);
    }
#pragma unroll
    for (int nn = 0; nn < 4; nn++)
        T[(size_t)(n0 + nn) * HID + lane] = f2bfu(acc[nn]);
}

__global__ void gemm_bn(const float* F, const float* W,
                        const float* scale, const float* shift, unsigned short* T) {
    int wid = (blockIdx.x * blockDim.x + threadIdx.x) >> 6;
    int n0 = wid * 4;
    if (n0 >= N_NODES) return;
    int lane = threadIdx.x & 63;
    float sc = scale[lane];
    float sh = shift[lane];
    float a[4];
#pragma unroll
    for (int nn = 0; nn < 4; nn++) {
        float f = F[(size_t)(n0 + nn) * HID + lane];
        a[nn] = fmaxf(f * sc + sh, 0.0f);
    }
    float acc[4] = { 0.0f, 0.0f, 0.0f, 0.0f };
    const float* Wp = W + lane;
#pragma unroll
    for (int k = 0; k < HID; k++) {
        float w = Wp[k * HID];
#pragma unroll
        for (int nn = 0; nn < 4; nn++)
            acc[nn] = fmaf(bcast(a[nn], k), w, acc[nn]);
    }
#pragma unroll
    for (int nn = 0; nn < 4; nn++)
        T[(size_t)(n0 + nn) * HID + lane] = f2bfu(acc[nn]);
}

// ---- aggregation: one wave per node, lane = g*8+c ----
// g = lane>>3 : edge slot within a chunk of 8 edges
// c = lane&7  : feature chunk (8 bf16 = one uint4 = 16B)
__global__ void agg_mid(const unsigned short* T, const int* row_start, const int* csr,
                        const float* dis, const float* bias, float* F) {
    int wid = (blockIdx.x * blockDim.x + threadIdx.x) >> 6;
    if (wid >= N_NODES) return;
    int lane = threadIdx.x & 63;
    int g = lane >> 3;
    int c = lane & 7;
    float dn = dis[wid];
    float acc[8];
#pragma unroll
    for (int k = 0; k < 8; k++) acc[k] = 0.0f;
    // self-loop term (weight dn inside acc; whole acc gets *dn at the end)
    if (g == 0) {
        uint4 v = ((const uint4*)(T + (size_t)wid * HID))[c];
        fma8(acc, v, dn);
    }
    int s0 = row_start[wid];
    int s1 = row_start[wid + 1];
    for (int e = s0; e < s1; e += 16) {
        int iA = e + g;
        int iB = e + 8 + g;
        int mA = iA < s1;
        int mB = iB < s1;
        int sA = csr[mA ? iA : s0];
        int sB = csr[mB ? iB : s0];
        float dA = mA ? dis[sA] : 0.0f;
        float dB = mB ? dis[sB] : 0.0f;
        uint4 vA = ((const uint4*)(T + (size_t)sA * HID))[c];
        uint4 vB = ((const uint4*)(T + (size_t)sB * HID))[c];
        fma8(acc, vA, dA);
        fma8(acc, vB, dB);
    }
    // reduce over the 8 edge-slot groups (xor strides 8,16,32)
#pragma unroll
    for (int k = 0; k < 8; k++) {
        float v = acc[k];
        v += __shfl_xor(v, 8);
        v += __shfl_xor(v, 16);
        v += __shfl_xor(v, 32);
        acc[k] = v;
    }
    if (g == 0) {
        const float4* bp = (const float4*)(bias + c * 8);
        float4 b0 = bp[0];
        float4 b1 = bp[1];
        float4 r0, r1;
        r0.x = b0.x + dn * acc[0];
        r0.y = b0.y + dn * acc[1];
        r0.z = b0.z + dn * acc[2];
        r0.w = b0.w + dn * acc[3];
        r1.x = b1.x + dn * acc[4];
        r1.y = b1.y + dn * acc[5];
        r1.z = b1.z + dn * acc[6];
        r1.w = b1.w + dn * acc[7];
        float4* o = (float4*)(F + (size_t)wid * HID + c * 8);
        o[0] = r0;
        o[1] = r1;
    }
}

__global__ void agg_out(const unsigned short* T, const int* row_start, const int* csr,
                        const float* dis, const float* bias, float* out) {
    int wid = (blockIdx.x * blockDim.x + threadIdx.x) >> 6;
    if (wid >= N_NODES) return;
    int lane = threadIdx.x & 63;
    int g = lane >> 3;
    int c = lane & 7;
    float dn = dis[wid];
    float acc[8];
#pragma unroll
    for (int k = 0; k < 8; k++) acc[k] = 0.0f;
    if (g == 0) {
        uint4 v = ((const uint4*)(T + (size_t)wid * HID))[c];
        fma8(acc, v, dn);
    }
    int s0 = row_start[wid];
    int s1 = row_start[wid + 1];
    for (int e = s0; e < s1; e += 16) {
        int iA = e + g;
        int iB = e + 8 + g;
        int mA = iA < s1;
        int mB = iB < s1;
        int sA = csr[mA ? iA : s0];
        int sB = csr[mB ? iB : s0];
        float dA = mA ? dis[sA] : 0.0f;
        float dB = mB ? dis[sB] : 0.0f;
        uint4 vA = ((const uint4*)(T + (size_t)sA * HID))[c];
        uint4 vB = ((const uint4*)(T + (size_t)sB * HID))[c];
        fma8(acc, vA, dA);
        fma8(acc, vB, dB);
    }
#pragma unroll
    for (int k = 0; k < 8; k++) {
        float v = acc[k];
        v += __shfl_xor(v, 8);
        v += __shfl_xor(v, 16);
        v += __shfl_xor(v, 32);
        acc[k] = v;
    }
    if (g == 0) {
        const float4* bp = (const float4*)(bias + c * 8);
        float4 b0 = bp[0];
        float4 b1 = bp[1];
        float4 r0, r1;
        r0.x = b0.x + dn * acc[0];
        r0.y = b0.y + dn * acc[1];
        r0.z = b0.z + dn * acc[2];
        r0.w = b0.w + dn * acc[3];
        r1.x = b1.x + dn * acc[4];
        r1.y = b1.y + dn * acc[5];
        r1.z = b1.z + dn * acc[6];
        r1.w = b1.w + dn * acc[7];
        float4* o;
        if (c < 4)
            o = (float4*)(out + (size_t)wid * LAT + c * 8);
        else
            o = (float4*)(out + (size_t)N_NODES * LAT + (size_t)wid * LAT + (c - 4) * 8);
        o[0] = r0;
        o[1] = r1;
    }
}

__global__ void stats_kernel(const float* F, float* stats) {
    int lane = threadIdx.x & 63;
    int wv = threadIdx.x >> 6;
    float s = 0.0f;
    float q = 0.0f;
    for (int r = blockIdx.x * 4 + wv; r < N_NODES; r += gridDim.x * 4) {
        float v = F[(size_t)r * HID + lane];
        s += v;
        q += v * v;
    }
    __shared__ float ls[256];
    __shared__ float lq[256];
    ls[threadIdx.x] = s;
    lq[threadIdx.x] = q;
    __syncthreads();
    if (threadIdx.x < 64) {
        s = ls[threadIdx.x] + ls[64 + threadIdx.x] + ls[128 + threadIdx.x] + ls[192 + threadIdx.x];
        q = lq[threadIdx.x] + lq[64 + threadIdx.x] + lq[128 + threadIdx.x] + lq[192 + threadIdx.x];
        atomicAdd(&stats[lane], s);
        atomicAdd(&stats[64 + lane], q);
    }
}

__global__ void finalize_bn(const float* stats, const void* g, const void* beta,
                            const int* flags, int gflag, int bflag,
                            float* scale, float* shift) {
    int j = threadIdx.x;
    if (j >= HID) return;
    float inv_n = 1.0f / (float)N_NODES;
    float mean = stats[j] * inv_n;
    float var = stats[64 + j] * inv_n - mean * mean;
    float sc = loadf(g, j, flags[gflag]) * rsqrtf(var + BN_EPS);
    scale[j] = sc;
    shift[j] = loadf(beta, j, flags[bflag]) - mean * sc;
}

extern "C" void kernel_launch(void* const* d_in, const int* in_sizes, int n_in,
                              void* d_out, int out_size, void* d_ws, size_t ws_size,
                              hipStream_t stream) {
    (void)in_sizes;
    (void)n_in;
    const void* x   = d_in[0];
    const void* ei  = d_in[1];
    const void* W1  = d_in[2];
    const void* b1  = d_in[3];
    const void* g1  = d_in[4];
    const void* be1 = d_in[5];
    const void* W2  = d_in[6];
    const void* b2  = d_in[7];
    const void* g2  = d_in[8];
    const void* be2 = d_in[9];
    const void* Wmu = d_in[10];
    const void* bmu = d_in[11];
    const void* Wls = d_in[12];
    const void* bls = d_in[13];
    float* out = (float*)d_out;

    char* base = (char*)d_ws;
    size_t off = 0;
    int* staged = (int*)(base + off);
    off += (size_t)N_EDGES * 4;        off = (off + 511) & ~(size_t)511;
    int* csr = (int*)(base + off);
    off += (size_t)N_EDGES * 4;        off = (off + 511) & ~(size_t)511;
    unsigned short* T = (unsigned short*)(base + off);
    off += (size_t)N_NODES * HID * 2;  off = (off + 511) & ~(size_t)511;
    float* F = (float*)(base + off);
    off += (size_t)N_NODES * HID * 4;  off = (off + 511) & ~(size_t)511;
    float* dis = (float*)(base + off);
    off += (size_t)N_NODES * 4;        off = (off + 511) & ~(size_t)511;
    int* row_start = (int*)(base + off);
    off += (size_t)(N_NODES + 1) * 4;  off = (off + 511) & ~(size_t)511;
    int* bcnt = (int*)(base + off);
    off += NBUCKET * 4;                off = (off + 511) & ~(size_t)511;
    int* bbase = (int*)(base + off);
    off += (NBUCKET + 1) * 4;          off = (off + 511) & ~(size_t)511;
    int* bcur = (int*)(base + off);
    off += NBUCKET * 4;                off = (off + 511) & ~(size_t)511;
    int* flags = (int*)(base + off);
    off += 512;                        off = (off + 511) & ~(size_t)511;
    float* W1f = (float*)(base + off);
    off += (size_t)IN_DIM * HID * 4;   off = (off + 511) & ~(size_t)511;
    float* W2f = (float*)(base + off);
    off += (size_t)HID * HID * 4;      off = (off + 511) & ~(size_t)511;
    float* Wcatf = (float*)(base + off);
    off += (size_t)HID * HID * 4;      off = (off + 511) & ~(size_t)511;
    float* b1f = (float*)(base + off);
    off += HID * 4;                    off = (off + 511) & ~(size_t)511;
    float* b2f = (float*)(base + off);
    off += HID * 4;                    off = (off + 511) & ~(size_t)511;
    float* bcatf = (float*)(base + off);
    off += HID * 4;                    off = (off + 511) & ~(size_t)511;
    float* stats = (float*)(base + off);
    off += 256 * 4;                    off = (off + 511) & ~(size_t)511;
    float* scale1 = (float*)(base + off);
    off += HID * 4;                    off = (off + 511) & ~(size_t)511;
    float* shift1 = (float*)(base + off);
    off += HID * 4;                    off = (off + 511) & ~(size_t)511;
    float* scale2 = (float*)(base + off);
    off += HID * 4;                    off = (off + 511) & ~(size_t)511;
    float* shift2 = (float*)(base + off);
    off += HID * 4;

    const int BT = 256;
    int gW   = (N_NODES * 64 + BT - 1) / BT;         // 25000 (wave per node)
    int gG   = ((N_NODES / 4) * 64 + BT - 1) / BT;   // 6250  (wave per 4 nodes)
    int gOut = (out_size + BT - 1) / BT;
    int gCv  = (IN_DIM * HID + 2 * HID * HID + 3 * HID + BT - 1) / BT;

    if (ws_size < off) {
        stamp_kernel<<<gOut, BT, 0, stream>>>(out, out_size, 6.8e37f);
        return;
    }

    detect_all<<<1, 896, 0, stream>>>((const int*)ei, x, W1, b1, g1, be1, W2, b2,
                                      g2, be2, Wmu, bmu, Wls, bls, flags);
    zero_misc<<<2, BT, 0, stream>>>(stats, bcnt);
    convert_weights<<<gCv, BT, 0, stream>>>(W1, W2, Wmu, Wls, b1, b2, bmu, bls,
                                            flags, W1f, W2f, Wcatf, b1f, b2f, bcatf);

    // bucketed CSR build
    bucket_hist<<<NBLK_E, BT, 0, stream>>>(ei, flags, bcnt);
    bucket_scan<<<1, BT, 0, stream>>>(bcnt, bbase, bcur, row_start);
    bucket_scatter<<<NBLK_E, BT, 0, stream>>>(ei, flags, bcur, staged);
    csr_build<<<NBUCKET, BT, 0, stream>>>(bbase, staged, dis, row_start, csr);

    // layer 1
    gemm_l1<<<gG, BT, 0, stream>>>(x, flags, W1f, T);
    agg_mid<<<gW, BT, 0, stream>>>(T, row_start, csr, dis, b1f, F);
    stats_kernel<<<256, BT, 0, stream>>>(F, stats);
    finalize_bn<<<1, 64, 0, stream>>>(stats, g1, be1, flags, 4, 5, scale1, shift1);

    // layer 2
    gemm_bn<<<gG, BT, 0, stream>>>(F, W2f, scale1, shift1, T);
    agg_mid<<<gW, BT, 0, stream>>>(T, row_start, csr, dis, b2f, F);
    stats_kernel<<<256, BT, 0, stream>>>(F, stats + 128);
    finalize_bn<<<1, 64, 0, stream>>>(stats + 128, g2, be2, flags, 8, 9, scale2, shift2);

    // layer 3 -> output (fp32)
    gemm_bn<<<gG, BT, 0, stream>>>(F, Wcatf, scale2, shift2, T);
    agg_out<<<gW, BT, 0, stream>>>(T, row_start, csr, dis, bcatf, out);
}

// Round 6
// 541.884 us; speedup vs baseline: 1.8607x; 1.0218x over previous
//
#include <hip/hip_runtime.h>
#include <stdint.h>

#define N_NODES 100000
#define N_EDGES 3200000
#define IN_DIM  81
#define HID     64
#define LAT     32
#define BN_EPS  1e-5f
#define NBUCKET 391      /* ceil(N_NODES/256) */
#define EPB     8192     /* edges per block in bucket passes */
#define NBLK_E  391      /* ceil(N_EDGES/EPB) */

__device__ __forceinline__ float bfu2f(unsigned short u) {
    return __uint_as_float(((uint32_t)u) << 16);
}
__device__ __forceinline__ unsigned short f2bfu(float f) {
    uint32_t x = __float_as_uint(f);
    return (unsigned short)((x + 0x7FFFu + ((x >> 16) & 1u)) >> 16);
}
__device__ __forceinline__ float loadf(const void* p, size_t i, int fp32) {
    if (fp32) return ((const float*)p)[i];
    return bfu2f(((const unsigned short*)p)[i]);
}
__device__ __forceinline__ int load_dst(const void* ei, int f64, long e) {
    if (f64) return (int)(((const long long*)ei)[(size_t)N_EDGES + e]);
    return ((const int*)ei)[(size_t)N_EDGES + e];
}
__device__ __forceinline__ int load_src(const void* ei, int f64, long e) {
    if (f64) return (int)(((const long long*)ei)[e]);
    return ((const int*)ei)[e];
}
// wave-uniform broadcast of lane k's value (k must be compile-time constant)
__device__ __forceinline__ float bcast(float v, int k) {
    return __int_as_float(__builtin_amdgcn_readlane(__float_as_int(v), k));
}

// unpack 8 bf16 (uint4) and fma into acc[8] with scalar weight d
__device__ __forceinline__ void fma8(float* acc, uint4 v, float d) {
    acc[0] = fmaf(__uint_as_float(v.x << 16), d, acc[0]);
    acc[1] = fmaf(__uint_as_float(v.x & 0xffff0000u), d, acc[1]);
    acc[2] = fmaf(__uint_as_float(v.y << 16), d, acc[2]);
    acc[3] = fmaf(__uint_as_float(v.y & 0xffff0000u), d, acc[3]);
    acc[4] = fmaf(__uint_as_float(v.z << 16), d, acc[4]);
    acc[5] = fmaf(__uint_as_float(v.z & 0xffff0000u), d, acc[5]);
    acc[6] = fmaf(__uint_as_float(v.w << 16), d, acc[6]);
    acc[7] = fmaf(__uint_as_float(v.w & 0xffff0000u), d, acc[7]);
}

__global__ void stamp_kernel(float* out, int n, float v) {
    int i = blockIdx.x * blockDim.x + threadIdx.x;
    if (i < n) out[i] = v;
}

// flags[0]: edge int64?  flags[1+b]: per-float-input fp32?
// One wave per buffer (w=0..12) + w=13 edge-dtype probe + w=14/15 zero misc.
__global__ void detect_all(const int* ei_raw,
                           const void* x, const void* W1, const void* b1,
                           const void* g1, const void* be1, const void* W2,
                           const void* b2, const void* g2, const void* be2,
                           const void* Wmu, const void* bmu, const void* Wls,
                           const void* bls, int* flags,
                           float* stats, int* bcnt) {
    int w = threadIdx.x >> 6;
    int lane = threadIdx.x & 63;
    if (w == 14) {
        for (int i = lane; i < 256; i += 64) stats[i] = 0.0f;
        return;
    }
    if (w == 15) {
        for (int i = lane; i < NBUCKET; i += 64) bcnt[i] = 0;
        return;
    }
    if (w == 13) {
        int acc = ei_raw[2 * lane * 11003 + 1] |
                  ei_raw[2 * (lane + 64) * 11003 + 1];
        unsigned long long b = __ballot(acc != 0);
        if (lane == 0) flags[0] = (b == 0ull) ? 1 : 0;
        return;
    }
    const void* bufs[13] = { x, W1, b1, g1, be1, W2, b2, g2, be2, Wmu, bmu, Wls, bls };
    const int   ns[13]   = { 512, 512, 64, 64, 64, 512, 64, 64, 64, 512, 32, 512, 32 };
    const unsigned short* u = (const unsigned short*)bufs[w];
    int n = ns[w];
    int evenZero = 0;
    bool oddNz = false, anyNz = false, big = false;
    for (int i = lane; i < n; i += 64) {
        unsigned short s = u[i];
        if (s) anyNz = true;
        if (i & 1) { if (s) oddNz = true; }
        else {
            if ((s & 0x7F80u) == 0x7F80u) big = true;
            else if (fabsf(bfu2f(s)) > 100.0f) big = true;
            if (s == 0) evenZero++;
        }
    }
    unsigned long long anyB = __ballot(anyNz);
    unsigned long long oddB = __ballot(oddNz);
    unsigned long long bigB = __ballot(big);
#pragma unroll
    for (int o = 1; o < 64; o <<= 1) evenZero += __shfl_xor(evenZero, o);
    if (lane == 0) {
        int fp32 = 0;
        if (anyB != 0ull) {
            if (bigB != 0ull) fp32 = 1;
            else if (evenZero >= n / 4 && oddB != 0ull) fp32 = 1;
        }
        flags[1 + w] = fp32;
    }
}

__global__ void convert_weights(const void* W1, const void* W2,
                                const void* Wmu, const void* Wls,
                                const void* b1, const void* b2,
                                const void* bmu, const void* bls,
                                const int* flags,
                                float* W1f, float* W2f, float* Wcatf,
                                float* b1f, float* b2f, float* bcatf) {
    int i = blockIdx.x * blockDim.x + threadIdx.x;
    if (i < IN_DIM * HID) { W1f[i] = loadf(W1, i, flags[2]); return; }
    i -= IN_DIM * HID;
    if (i < HID * HID) { W2f[i] = loadf(W2, i, flags[6]); return; }
    i -= HID * HID;
    if (i < HID * HID) {
        int k = i >> 6;
        int j = i & 63;
        if (j < LAT) Wcatf[i] = loadf(Wmu, (size_t)k * LAT + j, flags[10]);
        else         Wcatf[i] = loadf(Wls, (size_t)k * LAT + (j - LAT), flags[12]);
        return;
    }
    i -= HID * HID;
    if (i < HID) { b1f[i] = loadf(b1, i, flags[3]); return; }
    i -= HID;
    if (i < HID) { b2f[i] = loadf(b2, i, flags[7]); return; }
    i -= HID;
    if (i < HID) {
        if (i < LAT) bcatf[i] = loadf(bmu, i, flags[11]);
        else         bcatf[i] = loadf(bls, i - LAT, flags[13]);
    }
}

// ---- bucketed CSR build (counting sort by dst>>8) ----
// K1: per-block LDS histogram of dst buckets -> global bucket counts
__global__ void bucket_hist(const void* ei, const int* flags, int* bcnt) {
    __shared__ int h[NBUCKET];
    for (int i = threadIdx.x; i < NBUCKET; i += 256) h[i] = 0;
    __syncthreads();
    int f64 = flags[0];
    long e0 = (long)blockIdx.x * EPB;
    for (int i = 0; i < EPB / 256; i++) {
        long e = e0 + i * 256 + threadIdx.x;
        if (e < N_EDGES) atomicAdd(&h[load_dst(ei, f64, e) >> 8], 1);
    }
    __syncthreads();
    for (int i = threadIdx.x; i < NBUCKET; i += 256)
        if (h[i]) atomicAdd(&bcnt[i], h[i]);
}

// K2: exclusive scan of 391 bucket counts (512-slot LDS scan, 256 threads)
__global__ void bucket_scan(const int* bcnt, int* bbase, int* bcur, int* row_start) {
    __shared__ int sd[512];
    int t = threadIdx.x;
    int v0 = (t < NBUCKET) ? bcnt[t] : 0;
    int v1 = (t + 256 < NBUCKET) ? bcnt[t + 256] : 0;
    sd[t] = v0;
    sd[t + 256] = v1;
    __syncthreads();
    for (int off = 1; off < 256; off <<= 1) {       // scan lower half
        int x = (t >= off) ? sd[t - off] : 0;
        __syncthreads();
        sd[t] += x;
        __syncthreads();
    }
    int low_total = sd[255];
    for (int off = 1; off < 256; off <<= 1) {       // scan upper half
        int x = (t >= off) ? sd[256 + t - off] : 0;
        __syncthreads();
        sd[256 + t] += x;
        __syncthreads();
    }
    if (t < NBUCKET) {
        int excl = sd[t] - v0;
        bbase[t] = excl;
        bcur[t] = excl;
    }
    int j = 256 + t;
    if (j < NBUCKET) {
        int excl = sd[j] + low_total - v1;
        bbase[j] = excl;
        bcur[j] = excl;
    }
    if (t == 0) {
        bbase[NBUCKET] = N_EDGES;
        row_start[N_NODES] = N_EDGES;
    }
}

// K3: scatter edges into bucket-contiguous staging; record = (dst&255)<<17 | src
__global__ void bucket_scatter(const void* ei, const int* flags, int* bcur,
                               int* staged) {
    __shared__ int h[NBUCKET];
    __shared__ int lbase[NBUCKET];
    __shared__ int cnt[NBUCKET];
    for (int i = threadIdx.x; i < NBUCKET; i += 256) { h[i] = 0; cnt[i] = 0; }
    __syncthreads();
    int f64 = flags[0];
    long e0 = (long)blockIdx.x * EPB;
    for (int i = 0; i < EPB / 256; i++) {
        long e = e0 + i * 256 + threadIdx.x;
        if (e < N_EDGES) atomicAdd(&h[load_dst(ei, f64, e) >> 8], 1);
    }
    __syncthreads();
    for (int i = threadIdx.x; i < NBUCKET; i += 256)
        lbase[i] = h[i] ? atomicAdd(&bcur[i], h[i]) : 0;
    __syncthreads();
    for (int i = 0; i < EPB / 256; i++) {
        long e = e0 + i * 256 + threadIdx.x;
        if (e < N_EDGES) {
            int d = load_dst(ei, f64, e);
            int s = load_src(ei, f64, e);
            int b = d >> 8;
            int off = atomicAdd(&cnt[b], 1);
            staged[lbase[b] + off] = ((d & 255) << 17) | s;
        }
    }
}

// K4: one block per bucket: LDS deg/scan/cursors -> dis, row_start, csr
__global__ void csr_build(const int* bbase, const int* staged, float* dis,
                          int* row_start, int* csr) {
    int b = blockIdx.x;
    int t = threadIdx.x;
    int n0 = b << 8;
    int nn = N_NODES - n0;
    if (nn > 256) nn = 256;
    int e0 = bbase[b];
    int e1 = bbase[b + 1];
    __shared__ int ldeg[256];
    __shared__ int lcur[256];
    __shared__ int sd[256];
    ldeg[t] = 0;
    __syncthreads();
    for (int i = e0 + t; i < e1; i += 256)
        atomicAdd(&ldeg[staged[i] >> 17], 1);
    __syncthreads();
    int v = ldeg[t];
    sd[t] = v;
    __syncthreads();
    for (int off = 1; off < 256; off <<= 1) {
        int x = (t >= off) ? sd[t - off] : 0;
        __syncthreads();
        sd[t] += x;
        __syncthreads();
    }
    int excl = sd[t] - v;
    if (t < nn) {
        dis[n0 + t] = rsqrtf((float)(v + 1));
        row_start[n0 + t] = e0 + excl;
    }
    lcur[t] = e0 + excl;
    __syncthreads();
    for (int i = e0 + t; i < e1; i += 256) {
        int rec = staged[i];
        int pos = atomicAdd(&lcur[rec >> 17], 1);
        csr[pos] = rec & 0x1FFFF;
    }
}

// ---- dense layers: one wave per 4 nodes, lane = output feature ----
__global__ void gemm_l1(const void* X, const int* flags, const float* W,
                        unsigned short* T) {
    int wid = (blockIdx.x * blockDim.x + threadIdx.x) >> 6;
    int n0 = wid * 4;
    if (n0 >= N_NODES) return;
    int lane = threadIdx.x & 63;
    int fp = flags[1];
    float xa[4], xb[4];
#pragma unroll
    for (int nn = 0; nn < 4; nn++) {
        size_t base = (size_t)(n0 + nn) * IN_DIM;
        xa[nn] = loadf(X, base + lane, fp);
        xb[nn] = (lane < IN_DIM - 64) ? loadf(X, base + 64 + lane, fp) : 0.0f;
    }
    float acc[4] = { 0.0f, 0.0f, 0.0f, 0.0f };
    const float* Wp = W + lane;
#pragma unroll
    for (int k = 0; k < 64; k++) {
        float w = Wp[k * HID];
#pragma unroll
        for (int nn = 0; nn < 4; nn++)
            acc[nn] = fmaf(bcast(xa[nn], k), w, acc[nn]);
    }
#pragma unroll
    for (int k = 0; k < IN_DIM - 64; k++) {
        float w = Wp[(64 + k) * HID];
#pragma unroll
        for (int nn = 0; nn < 4; nn++)
            acc[nn] = fmaf(bcast(xb[nn], k), w, acc[nn]);
    }
#pragma unroll
    for (int nn = 0; nn < 4; nn++)
        T[(size_t)(n0 + nn) * HID + lane] = f2bfu(acc[nn]);
}

__global__ void gemm_bn(const float* F, const float* W,
                        const float* scale, const float* shift, unsigned short* T) {
    int wid = (blockIdx.x * blockDim.x + threadIdx.x) >> 6;
    int n0 = wid * 4;
    if (n0 >= N_NODES) return;
    int lane = threadIdx.x & 63;
    float sc = scale[lane];
    float sh = shift[lane];
    float a[4];
#pragma unroll
    for (int nn = 0; nn < 4; nn++) {
        float f = F[(size_t)(n0 + nn) * HID + lane];
        a[nn] = fmaxf(f * sc + sh, 0.0f);
    }
    float acc[4] = { 0.0f, 0.0f, 0.0f, 0.0f };
    const float* Wp = W + lane;
#pragma unroll
    for (int k = 0; k < HID; k++) {
        float w = Wp[k * HID];
#pragma unroll
        for (int nn = 0; nn < 4; nn++)
            acc[nn] = fmaf(bcast(a[nn], k), w, acc[nn]);
    }
#pragma unroll
    for (int nn = 0; nn < 4; nn++)
        T[(size_t)(n0 + nn) * HID + lane] = f2bfu(acc[nn]);
}

// ---- aggregation: one wave per node, lane = g*8+c ----
// g = lane>>3 : edge slot; c = lane&7 : feature chunk (8 bf16 = uint4 = 16B)
// 4 independent 8-edge chains per iteration (32 edges) -> 2x MLP vs 2 chains;
// masked chains gather a broadcast address (cheap).
__global__ void agg_mid(const unsigned short* T, const int* row_start, const int* csr,
                        const float* dis, const float* bias, float* F) {
    int wid = (blockIdx.x * blockDim.x + threadIdx.x) >> 6;
    if (wid >= N_NODES) return;
    int lane = threadIdx.x & 63;
    int g = lane >> 3;
    int c = lane & 7;
    float dn = dis[wid];
    float acc[8];
#pragma unroll
    for (int k = 0; k < 8; k++) acc[k] = 0.0f;
    // self-loop term
    if (g == 0) {
        uint4 v = ((const uint4*)(T + (size_t)wid * HID))[c];
        fma8(acc, v, dn);
    }
    int s0 = row_start[wid];
    int s1 = row_start[wid + 1];
    for (int e = s0; e < s1; e += 32) {
        int i0 = e + g;
        int i1 = e + 8 + g;
        int i2 = e + 16 + g;
        int i3 = e + 24 + g;
        int m0 = i0 < s1, m1 = i1 < s1, m2 = i2 < s1, m3 = i3 < s1;
        int n0i = csr[m0 ? i0 : s0];
        int n1i = csr[m1 ? i1 : s0];
        int n2i = csr[m2 ? i2 : s0];
        int n3i = csr[m3 ? i3 : s0];
        float d0 = m0 ? dis[n0i] : 0.0f;
        float d1 = m1 ? dis[n1i] : 0.0f;
        float d2 = m2 ? dis[n2i] : 0.0f;
        float d3 = m3 ? dis[n3i] : 0.0f;
        uint4 v0 = ((const uint4*)(T + (size_t)n0i * HID))[c];
        uint4 v1 = ((const uint4*)(T + (size_t)n1i * HID))[c];
        uint4 v2 = ((const uint4*)(T + (size_t)n2i * HID))[c];
        uint4 v3 = ((const uint4*)(T + (size_t)n3i * HID))[c];
        fma8(acc, v0, d0);
        fma8(acc, v1, d1);
        fma8(acc, v2, d2);
        fma8(acc, v3, d3);
    }
    // reduce over the 8 edge-slot groups (xor strides 8,16,32)
#pragma unroll
    for (int k = 0; k < 8; k++) {
        float v = acc[k];
        v += __shfl_xor(v, 8);
        v += __shfl_xor(v, 16);
        v += __shfl_xor(v, 32);
        acc[k] = v;
    }
    if (g == 0) {
        const float4* bp = (const float4*)(bias + c * 8);
        float4 b0 = bp[0];
        float4 b1 = bp[1];
        float4 r0, r1;
        r0.x = b0.x + dn * acc[0];
        r0.y = b0.y + dn * acc[1];
        r0.z = b0.z + dn * acc[2];
        r0.w = b0.w + dn * acc[3];
        r1.x = b1.x + dn * acc[4];
        r1.y = b1.y + dn * acc[5];
        r1.z = b1.z + dn * acc[6];
        r1.w = b1.w + dn * acc[7];
        float4* o = (float4*)(F + (size_t)wid * HID + c * 8);
        o[0] = r0;
        o[1] = r1;
    }
}

__global__ void agg_out(const unsigned short* T, const int* row_start, const int* csr,
                        const float* dis, const float* bias, float* out) {
    int wid = (blockIdx.x * blockDim.x + threadIdx.x) >> 6;
    if (wid >= N_NODES) return;
    int lane = threadIdx.x & 63;
    int g = lane >> 3;
    int c = lane & 7;
    float dn = dis[wid];
    float acc[8];
#pragma unroll
    for (int k = 0; k < 8; k++) acc[k] = 0.0f;
    if (g == 0) {
        uint4 v = ((const uint4*)(T + (size_t)wid * HID))[c];
        fma8(acc, v, dn);
    }
    int s0 = row_start[wid];
    int s1 = row_start[wid + 1];
    for (int e = s0; e < s1; e += 32) {
        int i0 = e + g;
        int i1 = e + 8 + g;
        int i2 = e + 16 + g;
        int i3 = e + 24 + g;
        int m0 = i0 < s1, m1 = i1 < s1, m2 = i2 < s1, m3 = i3 < s1;
        int n0i = csr[m0 ? i0 : s0];
        int n1i = csr[m1 ? i1 : s0];
        int n2i = csr[m2 ? i2 : s0];
        int n3i = csr[m3 ? i3 : s0];
        float d0 = m0 ? dis[n0i] : 0.0f;
        float d1 = m1 ? dis[n1i] : 0.0f;
        float d2 = m2 ? dis[n2i] : 0.0f;
        float d3 = m3 ? dis[n3i] : 0.0f;
        uint4 v0 = ((const uint4*)(T + (size_t)n0i * HID))[c];
        uint4 v1 = ((const uint4*)(T + (size_t)n1i * HID))[c];
        uint4 v2 = ((const uint4*)(T + (size_t)n2i * HID))[c];
        uint4 v3 = ((const uint4*)(T + (size_t)n3i * HID))[c];
        fma8(acc, v0, d0);
        fma8(acc, v1, d1);
        fma8(acc, v2, d2);
        fma8(acc, v3, d3);
    }
#pragma unroll
    for (int k = 0; k < 8; k++) {
        float v = acc[k];
        v += __shfl_xor(v, 8);
        v += __shfl_xor(v, 16);
        v += __shfl_xor(v, 32);
        acc[k] = v;
    }
    if (g == 0) {
        const float4* bp = (const float4*)(bias + c * 8);
        float4 b0 = bp[0];
        float4 b1 = bp[1];
        float4 r0, r1;
        r0.x = b0.x + dn * acc[0];
        r0.y = b0.y + dn * acc[1];
        r0.z = b0.z + dn * acc[2];
        r0.w = b0.w + dn * acc[3];
        r1.x = b1.x + dn * acc[4];
        r1.y = b1.y + dn * acc[5];
        r1.z = b1.z + dn * acc[6];
        r1.w = b1.w + dn * acc[7];
        float4* o;
        if (c < 4)
            o = (float4*)(out + (size_t)wid * LAT + c * 8);
        else
            o = (float4*)(out + (size_t)N_NODES * LAT + (size_t)wid * LAT + (c - 4) * 8);
        o[0] = r0;
        o[1] = r1;
    }
}

__global__ void stats_kernel(const float* F, float* stats) {
    int lane = threadIdx.x & 63;
    int wv = threadIdx.x >> 6;
    float s = 0.0f;
    float q = 0.0f;
    for (int r = blockIdx.x * 4 + wv; r < N_NODES; r += gridDim.x * 4) {
        float v = F[(size_t)r * HID + lane];
        s += v;
        q += v * v;
    }
    __shared__ float ls[256];
    __shared__ float lq[256];
    ls[threadIdx.x] = s;
    lq[threadIdx.x] = q;
    __syncthreads();
    if (threadIdx.x < 64) {
        s = ls[threadIdx.x] + ls[64 + threadIdx.x] + ls[128 + threadIdx.x] + ls[192 + threadIdx.x];
        q = lq[threadIdx.x] + lq[64 + threadIdx.x] + lq[128 + threadIdx.x] + lq[192 + threadIdx.x];
        atomicAdd(&stats[lane], s);
        atomicAdd(&stats[64 + lane], q);
    }
}

__global__ void finalize_bn(const float* stats, const void* g, const void* beta,
                            const int* flags, int gflag, int bflag,
                            float* scale, float* shift) {
    int j = threadIdx.x;
    if (j >= HID) return;
    float inv_n = 1.0f / (float)N_NODES;
    float mean = stats[j] * inv_n;
    float var = stats[64 + j] * inv_n - mean * mean;
    float sc = loadf(g, j, flags[gflag]) * rsqrtf(var + BN_EPS);
    scale[j] = sc;
    shift[j] = loadf(beta, j, flags[bflag]) - mean * sc;
}

extern "C" void kernel_launch(void* const* d_in, const int* in_sizes, int n_in,
                              void* d_out, int out_size, void* d_ws, size_t ws_size,
                              hipStream_t stream) {
    (void)in_sizes;
    (void)n_in;
    const void* x   = d_in[0];
    const void* ei  = d_in[1];
    const void* W1  = d_in[2];
    const void* b1  = d_in[3];
    const void* g1  = d_in[4];
    const void* be1 = d_in[5];
    const void* W2  = d_in[6];
    const void* b2  = d_in[7];
    const void* g2  = d_in[8];
    const void* be2 = d_in[9];
    const void* Wmu = d_in[10];
    const void* bmu = d_in[11];
    const void* Wls = d_in[12];
    const void* bls = d_in[13];
    float* out = (float*)d_out;

    char* base = (char*)d_ws;
    size_t off = 0;
    int* staged = (int*)(base + off);
    off += (size_t)N_EDGES * 4;        off = (off + 511) & ~(size_t)511;
    int* csr = (int*)(base + off);
    off += (size_t)N_EDGES * 4;        off = (off + 511) & ~(size_t)511;
    unsigned short* T = (unsigned short*)(base + off);
    off += (size_t)N_NODES * HID * 2;  off = (off + 511) & ~(size_t)511;
    float* F = (float*)(base + off);
    off += (size_t)N_NODES * HID * 4;  off = (off + 511) & ~(size_t)511;
    float* dis = (float*)(base + off);
    off += (size_t)N_NODES * 4;        off = (off + 511) & ~(size_t)511;
    int* row_start = (int*)(base + off);
    off += (size_t)(N_NODES + 1) * 4;  off = (off + 511) & ~(size_t)511;
    int* bcnt = (int*)(base + off);
    off += NBUCKET * 4;                off = (off + 511) & ~(size_t)511;
    int* bbase = (int*)(base + off);
    off += (NBUCKET + 1) * 4;          off = (off + 511) & ~(size_t)511;
    int* bcur = (int*)(base + off);
    off += NBUCKET * 4;                off = (off + 511) & ~(size_t)511;
    int* flags = (int*)(base + off);
    off += 512;                        off = (off + 511) & ~(size_t)511;
    float* W1f = (float*)(base + off);
    off += (size_t)IN_DIM * HID * 4;   off = (off + 511) & ~(size_t)511;
    float* W2f = (float*)(base + off);
    off += (size_t)HID * HID * 4;      off = (off + 511) & ~(size_t)511;
    float* Wcatf = (float*)(base + off);
    off += (size_t)HID * HID * 4;      off = (off + 511) & ~(size_t)511;
    float* b1f = (float*)(base + off);
    off += HID * 4;                    off = (off + 511) & ~(size_t)511;
    float* b2f = (float*)(base + off);
    off += HID * 4;                    off = (off + 511) & ~(size_t)511;
    float* bcatf = (float*)(base + off);
    off += HID * 4;                    off = (off + 511) & ~(size_t)511;
    float* stats = (float*)(base + off);
    off += 256 * 4;                    off = (off + 511) & ~(size_t)511;
    float* scale1 = (float*)(base + off);
    off += HID * 4;                    off = (off + 511) & ~(size_t)511;
    float* shift1 = (float*)(base + off);
    off += HID * 4;                    off = (off + 511) & ~(size_t)511;
    float* scale2 = (float*)(base + off);
    off += HID * 4;                    off = (off + 511) & ~(size_t)511;
    float* shift2 = (float*)(base + off);
    off += HID * 4;

    const int BT = 256;
    int gW   = (N_NODES * 64 + BT - 1) / BT;         // 25000 (wave per node)
    int gG   = ((N_NODES / 4) * 64 + BT - 1) / BT;   // 6250  (wave per 4 nodes)
    int gOut = (out_size + BT - 1) / BT;
    int gCv  = (IN_DIM * HID + 2 * HID * HID + 3 * HID + BT - 1) / BT;

    if (ws_size < off) {
        stamp_kernel<<<gOut, BT, 0, stream>>>(out, out_size, 6.8e37f);
        return;
    }

    detect_all<<<1, 1024, 0, stream>>>((const int*)ei, x, W1, b1, g1, be1, W2, b2,
                                       g2, be2, Wmu, bmu, Wls, bls, flags,
                                       stats, bcnt);
    convert_weights<<<gCv, BT, 0, stream>>>(W1, W2, Wmu, Wls, b1, b2, bmu, bls,
                                            flags, W1f, W2f, Wcatf, b1f, b2f, bcatf);

    // bucketed CSR build
    bucket_hist<<<NBLK_E, BT, 0, stream>>>(ei, flags, bcnt);
    bucket_scan<<<1, BT, 0, stream>>>(bcnt, bbase, bcur, row_start);
    bucket_scatter<<<NBLK_E, BT, 0, stream>>>(ei, flags, bcur, staged);
    csr_build<<<NBUCKET, BT, 0, stream>>>(bbase, staged, dis, row_start, csr);

    // layer 1
    gemm_l1<<<gG, BT, 0, stream>>>(x, flags, W1f, T);
    agg_mid<<<gW, BT, 0, stream>>>(T, row_start, csr, dis, b1f, F);
    stats_kernel<<<256, BT, 0, stream>>>(F, stats);
    finalize_bn<<<1, 64, 0, stream>>>(stats, g1, be1, flags, 4, 5, scale1, shift1);

    // layer 2
    gemm_bn<<<gG, BT, 0, stream>>>(F, W2f, scale1, shift1, T);
    agg_mid<<<gW, BT, 0, stream>>>(T, row_start, csr, dis, b2f, F);
    stats_kernel<<<256, BT, 0, stream>>>(F, stats + 128);
    finalize_bn<<<1, 64, 0, stream>>>(stats + 128, g2, be2, flags, 8, 9, scale2, shift2);

    // layer 3 -> output (fp32)
    gemm_bn<<<gG, BT, 0, stream>>>(F, Wcatf, scale2, shift2, T);
    agg_out<<<gW, BT, 0, stream>>>(T, row_start, csr, dis, bcatf, out);
}